// Round 13
// baseline (189.203 us; speedup 1.0000x reference)
//
#include <hip/hip_runtime.h>
#include <hip/hip_fp16.h>
#include <math.h>

#define B_  16
#define H_  8
#define L_  512
#define DM_ 512
#define DK_ 64
#define LOG2E_ 1.44269504088896340736f
#define NLOG2E_H_ 0.72134752044f   // 0.5 * log2(e)

typedef _Float16 f16;
typedef __attribute__((ext_vector_type(2)))  __fp16   fp16v2;
typedef __attribute__((ext_vector_type(8)))  _Float16 f16x8;
typedef __attribute__((ext_vector_type(16))) float f32x16;

__device__ __forceinline__ unsigned pkrtz(float a, float b) {
    union { fp16v2 v; unsigned u; } cv;
    cv.v = __builtin_amdgcn_cvt_pkrtz(a, b);
    return cv.u;
}
// v_permlane32_swap_b32: x[lanes 32..63] <-> y[lanes 0..31]
__device__ __forceinline__ void plswap(unsigned &x, unsigned &y) {
    asm("v_permlane32_swap_b32 %0, %1" : "+v"(x), "+v"(y));
}

// ---------------------------------------------------------------------------
// MFMA fp16 GEMM core (unchanged from R12).
// ---------------------------------------------------------------------------
template<int XF16, int OUTF32, int TRANSOUT>
__device__ __forceinline__ void gemm_core(
    const void* __restrict__ Xv, const float* __restrict__ W,
    const float* __restrict__ bias, void* __restrict__ Yv,
    int row0, int col0, f16* lds)
{
    f16* Al = lds;
    f16* Bl = lds + 128 * 64;

    const int tid   = threadIdx.x;
    const int w     = tid >> 6;
    const int lane  = tid & 63;
    const int lq    = lane & 31;
    const int half_ = lane >> 5;
    const int wr    = w & 1;
    const int wc    = w >> 1;

    const int xr_r = tid >> 4;       // 0..31
    const int xr_c = tid & 15;       // float4 index
    const int xh_r = tid >> 3;       // 0..63
    const int xh_c = tid & 7;        // uint4 index

    f32x16 acc[2];
    #pragma unroll
    for (int rs = 0; rs < 2; ++rs)
        #pragma unroll
        for (int i = 0; i < 16; ++i) acc[rs][i] = 0.f;

    float4 xr[4], wreg[4];
    uint4  xh[2];

    {
        if (XF16) {
            const f16* X = (const f16*)Xv;
            #pragma unroll
            for (int j = 0; j < 2; ++j)
                xh[j] = *(const uint4*)&X[(size_t)(row0 + j * 64 + xh_r) * 512 + xh_c * 8];
        } else {
            const float* X = (const float*)Xv;
            #pragma unroll
            for (int j = 0; j < 4; ++j)
                xr[j] = *(const float4*)&X[(size_t)(row0 + j * 32 + xr_r) * 512 + xr_c * 4];
        }
        #pragma unroll
        for (int j = 0; j < 4; ++j)
            wreg[j] = *(const float4*)&W[(size_t)(col0 + j * 32 + xr_r) * 512 + xr_c * 4];
    }

    for (int t = 0; t < 8; ++t) {
        __syncthreads();
        {
            if (XF16) {
                #pragma unroll
                for (int j = 0; j < 2; ++j) {
                    const int r = j * 64 + xh_r;
                    *(uint4*)((char*)Al + ((r * 128 + xh_c * 16) ^ ((r & 7) << 4))) = xh[j];
                }
            } else {
                #pragma unroll
                for (int j = 0; j < 4; ++j) {
                    const int r = j * 32 + xr_r;
                    uint2 v;
                    v.x = pkrtz(xr[j].x, xr[j].y);
                    v.y = pkrtz(xr[j].z, xr[j].w);
                    *(uint2*)((char*)Al + ((r * 128 + xr_c * 8) ^ ((r & 7) << 4))) = v;
                }
            }
            #pragma unroll
            for (int j = 0; j < 4; ++j) {
                const int r = j * 32 + xr_r;
                uint2 v;
                v.x = pkrtz(wreg[j].x, wreg[j].y);
                v.y = pkrtz(wreg[j].z, wreg[j].w);
                *(uint2*)((char*)Bl + ((r * 128 + xr_c * 8) ^ ((r & 7) << 4))) = v;
            }
        }
        __syncthreads();

        if (t < 7) {
            const int k0 = (t + 1) * 64;
            if (XF16) {
                const f16* X = (const f16*)Xv;
                #pragma unroll
                for (int j = 0; j < 2; ++j)
                    xh[j] = *(const uint4*)&X[(size_t)(row0 + j * 64 + xh_r) * 512 + k0 + xh_c * 8];
            } else {
                const float* X = (const float*)Xv;
                #pragma unroll
                for (int j = 0; j < 4; ++j)
                    xr[j] = *(const float4*)&X[(size_t)(row0 + j * 32 + xr_r) * 512 + k0 + xr_c * 4];
            }
            #pragma unroll
            for (int j = 0; j < 4; ++j)
                wreg[j] = *(const float4*)&W[(size_t)(col0 + j * 32 + xr_r) * 512 + k0 + xr_c * 4];
        }

        const int ra0 = wr * 64 + lq;
        const int ra1 = wr * 64 + 32 + lq;
        const int rbc = wc * 32 + lq;
        #pragma unroll
        for (int ks = 0; ks < 4; ++ks) {
            const unsigned koff = ks * 32 + half_ * 16;
            f16x8 a0, a1, bf;
            if (TRANSOUT) {
                a0 = *(const f16x8*)((char*)Bl + ((ra0 * 128 + koff) ^ ((ra0 & 7) << 4)));
                a1 = *(const f16x8*)((char*)Bl + ((ra1 * 128 + koff) ^ ((ra1 & 7) << 4)));
                bf = *(const f16x8*)((char*)Al + ((rbc * 128 + koff) ^ ((rbc & 7) << 4)));
            } else {
                a0 = *(const f16x8*)((char*)Al + ((ra0 * 128 + koff) ^ ((ra0 & 7) << 4)));
                a1 = *(const f16x8*)((char*)Al + ((ra1 * 128 + koff) ^ ((ra1 & 7) << 4)));
                bf = *(const f16x8*)((char*)Bl + ((rbc * 128 + koff) ^ ((rbc & 7) << 4)));
            }
            acc[0] = __builtin_amdgcn_mfma_f32_32x32x16_f16(a0, bf, acc[0], 0, 0, 0);
            acc[1] = __builtin_amdgcn_mfma_f32_32x32x16_f16(a1, bf, acc[1], 0, 0, 0);
        }
    }

    if (TRANSOUT) {
        const int lg = row0 + wc * 32 + lq;
        const int bI = lg >> 9, ll = lg & 511;
        #pragma unroll
        for (int rs = 0; rs < 2; ++rs) {
            #pragma unroll
            for (int r = 0; r < 16; ++r) {
                const int n = col0 + wr * 64 + rs * 32 + (r & 3) + 8 * (r >> 2) + 4 * half_;
                const float v = acc[rs][r] + bias[n];
                ((f16*)Yv)[((size_t)(bI * 512 + n)) * 512 + ll] = (f16)v;
            }
        }
    } else {
        const float bv = bias[col0 + wc * 32 + lq];
        #pragma unroll
        for (int rs = 0; rs < 2; ++rs) {
            #pragma unroll
            for (int r = 0; r < 16; ++r) {
                const int row = row0 + wr * 64 + rs * 32 + (r & 3) + 8 * (r >> 2) + 4 * half_;
                const float v = acc[rs][r] + bv;
                const size_t off = (size_t)row * 512 + col0 + wc * 32 + lq;
                if (OUTF32) ((float*)Yv)[off] = v;
                else        ((f16*)Yv)[off]   = (f16)v;
            }
        }
    }
}

__global__ __launch_bounds__(512) void gemm_qkv(
    const float* __restrict__ query, const float* __restrict__ key,
    const float* __restrict__ value,
    const float* __restrict__ Wq, const float* __restrict__ bq,
    const float* __restrict__ Wk, const float* __restrict__ bk,
    const float* __restrict__ Wv, const float* __restrict__ bv,
    void* __restrict__ Qb, void* __restrict__ Kb, void* __restrict__ VT)
{
    __shared__ f16 lds[2 * 128 * 64];
    const int wg  = blockIdx.x;
    const int xcd = wg & 7;
    const int i   = wg >> 3;
    const int col = i & 3;
    const int p   = i >> 2;
    const int pg  = xcd * 24 + p;       // 0..191
    const int z   = pg >> 6;
    const int y   = pg & 63;
    const int row0 = y * 128, col0 = col * 128;

    if (z == 0)      gemm_core<0, 0, 0>(query, Wq, bq, Qb, row0, col0, lds);
    else if (z == 1) gemm_core<0, 0, 0>(key,   Wk, bk, Kb, row0, col0, lds);
    else             gemm_core<0, 0, 1>(value, Wv, bv, VT, row0, col0, lds);
}

__global__ __launch_bounds__(512) void gemm_o(
    const void* __restrict__ X, const float* __restrict__ Wo,
    const float* __restrict__ bo, void* __restrict__ Y)
{
    __shared__ f16 lds[2 * 128 * 64];
    const int wg  = blockIdx.x;
    const int xcd = wg & 7;
    const int i   = wg >> 3;
    const int col = i & 3;
    const int y   = xcd * 8 + (i >> 2);
    gemm_core<1, 1, 0>(X, Wo, bo, Y, y * 128, col * 128, lds);
}

// ---------------------------------------------------------------------------
// 1-wave flash attention with LDS-staged K/V tiles.
// Global loads are wave-contiguous full-line reads (8 lanes/row x 16B);
// LDS XOR-swizzled (chunk ^= row&7) on write and read; register staging
// issues tile t+1's loads right after tile t's ds_writes -> latency hidden
// under the whole tile compute.  No barriers (single wave per block).
// ---------------------------------------------------------------------------
__global__ __launch_bounds__(64) void attn_kernel(
    const f16* __restrict__ Q, const f16* __restrict__ K,
    const f16* __restrict__ VT, const float* __restrict__ Wg,
    const float* __restrict__ bg, const float* __restrict__ lam1,
    f16* __restrict__ ATT)
{
    __shared__ f16 Kl[64 * 64];   // 64 rows x 128B (8KB), swizzled chunks
    __shared__ f16 Vl[64 * 64];   // 8KB

    const int lane = threadIdx.x;     // 0..63
    const int lq   = lane & 31;
    const int half = lane >> 5;
    const int bh   = blockIdx.x;      // same bh -> same XCD
    const int b    = bh >> 3;
    const int h    = bh & 7;
    const int q0w  = blockIdx.y * 32;
    const int q    = q0w + lq;

    const int sr = lane >> 3;         // staging sub-row 0..7
    const int sc = lane & 7;          // staging chunk 0..7

    const float sg  = 1.f / (1.f + __expf(-lam1[0]));
    const float osg = 1.f - sg;

    // Q fragments (B-operand)
    f16x8 qh[4];
    {
        const f16* qrow = Q + ((size_t)(b * L_ + q) * DM_ + h * DK_);
        #pragma unroll
        for (int db = 0; db < 4; ++db)
            qh[db] = *(const f16x8*)&qrow[db * 16 + 8 * half];
    }

    // fused gamma: g = q_row . Wg^T + bg ; qp = (|g|+1)^-2
    float A0, A1, qpw;
    {
        float g0 = 0.f, g1 = 0.f;
        #pragma unroll
        for (int db = 0; db < 4; ++db)
            #pragma unroll
            for (int j = 0; j < 8; ++j) {
                const int d = db * 16 + 8 * half + j;
                const float qv = (float)qh[db][j];
                g0 = fmaf(qv, Wg[d], g0);
                g1 = fmaf(qv, Wg[64 + d], g1);
            }
        g0 += __shfl_xor(g0, 32);
        g1 += __shfl_xor(g1, 32);
        g0 += bg[0];
        g1 += bg[1];
        const float t0 = fabsf(g0) + 1.f, t1 = fabsf(g1) + 1.f;
        const float p0 = 1.f / (t0 * t0), p1 = 1.f / (t1 * t1);
        A0 = -NLOG2E_H_ * p0;       // c >= q (triu)
        A1 = -NLOG2E_H_ * p1;       // c <  q (tril)
        float mn = NLOG2E_H_ * fminf(p0, p1);
        #pragma unroll
        for (int off = 1; off < 64; off <<= 1) mn = fminf(mn, __shfl_xor(mn, off));
        qpw = mn;
    }

    f32x16 aS0, aS1, aA0, aA1;
    #pragma unroll
    for (int i = 0; i < 16; ++i) { aS0[i] = 0.f; aS1[i] = 0.f; aA0[i] = 0.f; aA1[i] = 0.f; }
    float m2 = -3.0e38f, sumS = 0.f, sumA = 0.f;

    const f16* Kbase = K  + ((size_t)(b * L_) * DM_ + h * DK_);
    const f16* Vbase = VT + ((size_t)(b * DM_ + h * DK_) * L_);

    uint4 kreg[8], vreg[8];
    // prologue: wave-contiguous full-line loads of tile 0
    #pragma unroll
    for (int p = 0; p < 8; ++p) {
        const int r = p * 8 + sr;
        kreg[p] = *(const uint4*)&Kbase[(size_t)r * DM_ + sc * 8];
        vreg[p] = *(const uint4*)&Vbase[(size_t)r * L_ + sc * 8];
    }

    for (int t = 0; t < 8; ++t) {
        const int c0 = t * 64;

        // staged regs -> LDS (swizzled, conflict-free)
        #pragma unroll
        for (int p = 0; p < 8; ++p) {
            const int r = p * 8 + sr;
            const unsigned off = r * 128 + (((unsigned)(sc ^ (r & 7))) << 4);
            *(uint4*)((char*)Kl + off) = kreg[p];
            *(uint4*)((char*)Vl + off) = vreg[p];
        }

        // issue next tile's global loads (regs free after ds_write issue)
        if (t < 7) {
            const int c1 = c0 + 64;
            #pragma unroll
            for (int p = 0; p < 8; ++p) {
                const int r = p * 8 + sr;
                kreg[p] = *(const uint4*)&Kbase[(size_t)(c1 + r) * DM_ + sc * 8];
                vreg[p] = *(const uint4*)&Vbase[(size_t)r * L_ + c1 + sc * 8];
            }
        }

        // fragment reads (swizzled; (32+lq)&7 == lq&7 so same xor)
        const unsigned fx = ((unsigned)(lq & 7)) << 4;
        f16x8 ka[4], kb2[4], vfa[4], vfb[4];
        #pragma unroll
        for (int db = 0; db < 4; ++db) {
            const unsigned ch = ((unsigned)(db * 2 + half)) << 4;
            ka[db]  = *(const f16x8*)((char*)Kl + lq * 128 + (ch ^ fx));
            kb2[db] = *(const f16x8*)((char*)Kl + (32 + lq) * 128 + (ch ^ fx));
            vfa[db] = *(const f16x8*)((char*)Vl + lq * 128 + (ch ^ fx));
            vfb[db] = *(const f16x8*)((char*)Vl + (32 + lq) * 128 + (ch ^ fx));
        }

        // S^T = K . Q^T
        f32x16 s2a, s2b;
        #pragma unroll
        for (int i = 0; i < 16; ++i) { s2a[i] = 0.f; s2b[i] = 0.f; }
        #pragma unroll
        for (int db = 0; db < 4; ++db) {
            s2a = __builtin_amdgcn_mfma_f32_32x32x16_f16(ka[db],  qh[db], s2a, 0, 0, 0);
            s2b = __builtin_amdgcn_mfma_f32_32x32x16_f16(kb2[db], qh[db], s2b, 0, 0, 0);
        }

        // online max with skip-rescale
        float tm = s2a[0];
        #pragma unroll
        for (int i = 1; i < 16; ++i) tm = fmaxf(tm, s2a[i]);
        #pragma unroll
        for (int i = 0; i < 16; ++i) tm = fmaxf(tm, s2b[i]);
        tm = fmaxf(tm, __shfl_xor(tm, 32));
        if (__any(tm > m2)) {
            const float nm = fmaxf(m2, tm);
            const float sc_ = exp2f((m2 - nm) * LOG2E_);
            m2 = nm;
            sumS *= sc_;
            #pragma unroll
            for (int r = 0; r < 16; ++r) {
                const float s_ = __shfl(sc_, (r & 3) + 8 * (r >> 2) + 4 * half);
                aS0[r] *= s_;
                aS1[r] *= s_;
            }
        }

        // P: exp, pack, permlane-swap into A-fragments, PV MFMAs
        const float nmL = m2 * LOG2E_;
        #pragma unroll
        for (int sub = 0; sub < 2; ++sub) {
            const f32x16& s2 = sub ? s2b : s2a;
            #pragma unroll
            for (int ksl = 0; ksl < 2; ++ksl) {
                const int rb = ksl * 8;
                float p[8];
                #pragma unroll
                for (int rr = 0; rr < 8; ++rr) {
                    p[rr] = exp2f(fmaf(s2[rb + rr], LOG2E_, -nmL));
                    sumS += p[rr];
                }
                union { unsigned u[4]; f16x8 v; } f;
                f.u[0] = pkrtz(p[0], p[1]);
                f.u[1] = pkrtz(p[2], p[3]);
                f.u[2] = pkrtz(p[4], p[5]);
                f.u[3] = pkrtz(p[6], p[7]);
                plswap(f.u[0], f.u[2]);
                plswap(f.u[1], f.u[3]);
                const int ks = sub * 2 + ksl;
                aS0 = __builtin_amdgcn_mfma_f32_32x32x16_f16(f.v, vfa[ks], aS0, 0, 0, 0);
                aS1 = __builtin_amdgcn_mfma_f32_32x32x16_f16(f.v, vfb[ks], aS1, 0, 0, 0);
            }
        }

        // adjacency branch (band-skip far tiles; diagonal tile never skipped)
        int gl_ = q0w - (c0 + 63);
        int gh_ = c0 - (q0w + 31);
        int dmin = gl_ > gh_ ? gl_ : gh_;
        if (dmin < 0) dmin = 0;
        if (qpw * (float)(dmin * dmin) < 40.0f) {
            #pragma unroll
            for (int sub = 0; sub < 2; ++sub) {
                #pragma unroll
                for (int ksl = 0; ksl < 2; ++ksl) {
                    float a[8];
                    #pragma unroll
                    for (int rr = 0; rr < 8; ++rr) {
                        const int kk = (rr & 3) + 8 * (rr >> 2) + 16 * ksl + 4 * half;
                        const int diff = q - (c0 + sub * 32 + kk);
                        const float fd = (float)diff;
                        const float coef = diff > 0 ? A1 : A0;
                        a[rr] = exp2f(coef * fd * fd);
                        sumA += a[rr];
                    }
                    union { unsigned u[4]; f16x8 v; } f;
                    f.u[0] = pkrtz(a[0], a[1]);
                    f.u[1] = pkrtz(a[2], a[3]);
                    f.u[2] = pkrtz(a[4], a[5]);
                    f.u[3] = pkrtz(a[6], a[7]);
                    plswap(f.u[0], f.u[2]);
                    plswap(f.u[1], f.u[3]);
                    const int ks = sub * 2 + ksl;
                    aA0 = __builtin_amdgcn_mfma_f32_32x32x16_f16(f.v, vfa[ks], aA0, 0, 0, 0);
                    aA1 = __builtin_amdgcn_mfma_f32_32x32x16_f16(f.v, vfb[ks], aA1, 0, 0, 0);
                }
            }
        }
    }

    // epilogue: mix branches, degree-normalize, store
    const float St = sumS + __shfl_xor(sumS, 32);
    const float At = sumA + __shfl_xor(sumA, 32);
    const float den = sg * St + osg * At + 1e-9f;
    #pragma unroll
    for (int r = 0; r < 16; ++r) {
        const int row = (r & 3) + 8 * (r >> 2) + 4 * half;
        const float dn = __shfl(den, row);
        const float o0 = (sg * aS0[r] + osg * aA0[r]) / dn;
        const float o1 = (sg * aS1[r] + osg * aA1[r]) / dn;
        const size_t base = (size_t)(b * L_ + q0w + row) * DM_ + h * DK_;
        ATT[base + lq]      = (f16)o0;
        ATT[base + 32 + lq] = (f16)o1;
    }
}

// ---------------------------------------------------------------------------
extern "C" void kernel_launch(void* const* d_in, const int* in_sizes, int n_in,
                              void* d_out, int out_size, void* d_ws, size_t ws_size,
                              hipStream_t stream)
{
    (void)in_sizes; (void)n_in; (void)out_size; (void)ws_size;
    const float* query = (const float*)d_in[0];
    const float* key   = (const float*)d_in[1];
    const float* value = (const float*)d_in[2];
    const float* Wq = (const float*)d_in[3];  const float* bq = (const float*)d_in[4];
    const float* Wk = (const float*)d_in[5];  const float* bk = (const float*)d_in[6];
    const float* Wv = (const float*)d_in[7];  const float* bv = (const float*)d_in[8];
    const float* Wg = (const float*)d_in[9];  const float* bg = (const float*)d_in[10];
    const float* lam1 = (const float*)d_in[11];
    const float* Wo = (const float*)d_in[12]; const float* bo = (const float*)d_in[13];

    f16* ws16 = (f16*)d_ws;
    const size_t NR = (size_t)B_ * L_ * DM_;
    f16* Kb  = ws16;
    f16* VTb = ws16 + NR;
    f16* Qb  = ws16 + 2 * NR;
    f16* ATTb = Qb;   // safe alias: each wave reads exactly the Q cells it later writes

    gemm_qkv<<<768, 512, 0, stream>>>(query, key, value, Wq, bq, Wk, bk, Wv, bv,
                                      Qb, Kb, VTb);

    dim3 ga(H_ * B_, L_ / 32);    // (128, 16), 64 threads = 1 wave per block
    attn_kernel<<<ga, 64, 0, stream>>>(Qb, Kb, VTb, Wg, bg, lam1, ATTb);

    gemm_o<<<256, 512, 0, stream>>>(Qb, Wo, bo, (float*)d_out);
}

// Round 14
// 99.558 us; speedup vs baseline: 1.9004x; 1.9004x over previous
//
#include <hip/hip_runtime.h>
#include <hip/hip_fp16.h>
#include <math.h>

#define B_  16
#define H_  8
#define L_  512
#define DM_ 512
#define DK_ 64
#define LOG2E_ 1.44269504088896340736f
#define NLOG2E_H_ 0.72134752044f   // 0.5 * log2(e)

typedef _Float16 f16;
typedef __attribute__((ext_vector_type(2)))  __fp16   fp16v2;
typedef __attribute__((ext_vector_type(8)))  _Float16 f16x8;
typedef __attribute__((ext_vector_type(16))) float f32x16;

__device__ __forceinline__ unsigned pkrtz(float a, float b) {
    union { fp16v2 v; unsigned u; } cv;
    cv.v = __builtin_amdgcn_cvt_pkrtz(a, b);
    return cv.u;
}
// v_permlane32_swap_b32: x[lanes 32..63] <-> y[lanes 0..31]
__device__ __forceinline__ void plswap(unsigned &x, unsigned &y) {
    asm("v_permlane32_swap_b32 %0, %1" : "+v"(x), "+v"(y));
}
// async global->LDS, 16B per lane; LDS dest = uniform base + lane*16
__device__ __forceinline__ void gl_lds16(const f16* g, f16* l) {
    __builtin_amdgcn_global_load_lds(
        (const __attribute__((address_space(1))) unsigned int*)g,
        (__attribute__((address_space(3))) unsigned int*)l, 16, 0, 0);
}

// ---------------------------------------------------------------------------
// MFMA fp16 GEMM core (unchanged from R12).
// ---------------------------------------------------------------------------
template<int XF16, int OUTF32, int TRANSOUT>
__device__ __forceinline__ void gemm_core(
    const void* __restrict__ Xv, const float* __restrict__ W,
    const float* __restrict__ bias, void* __restrict__ Yv,
    int row0, int col0, f16* lds)
{
    f16* Al = lds;
    f16* Bl = lds + 128 * 64;

    const int tid   = threadIdx.x;
    const int w     = tid >> 6;
    const int lane  = tid & 63;
    const int lq    = lane & 31;
    const int half_ = lane >> 5;
    const int wr    = w & 1;
    const int wc    = w >> 1;

    const int xr_r = tid >> 4;       // 0..31
    const int xr_c = tid & 15;       // float4 index
    const int xh_r = tid >> 3;       // 0..63
    const int xh_c = tid & 7;        // uint4 index

    f32x16 acc[2];
    #pragma unroll
    for (int rs = 0; rs < 2; ++rs)
        #pragma unroll
        for (int i = 0; i < 16; ++i) acc[rs][i] = 0.f;

    float4 xr[4], wreg[4];
    uint4  xh[2];

    {
        if (XF16) {
            const f16* X = (const f16*)Xv;
            #pragma unroll
            for (int j = 0; j < 2; ++j)
                xh[j] = *(const uint4*)&X[(size_t)(row0 + j * 64 + xh_r) * 512 + xh_c * 8];
        } else {
            const float* X = (const float*)Xv;
            #pragma unroll
            for (int j = 0; j < 4; ++j)
                xr[j] = *(const float4*)&X[(size_t)(row0 + j * 32 + xr_r) * 512 + xr_c * 4];
        }
        #pragma unroll
        for (int j = 0; j < 4; ++j)
            wreg[j] = *(const float4*)&W[(size_t)(col0 + j * 32 + xr_r) * 512 + xr_c * 4];
    }

    for (int t = 0; t < 8; ++t) {
        __syncthreads();
        {
            if (XF16) {
                #pragma unroll
                for (int j = 0; j < 2; ++j) {
                    const int r = j * 64 + xh_r;
                    *(uint4*)((char*)Al + ((r * 128 + xh_c * 16) ^ ((r & 7) << 4))) = xh[j];
                }
            } else {
                #pragma unroll
                for (int j = 0; j < 4; ++j) {
                    const int r = j * 32 + xr_r;
                    uint2 v;
                    v.x = pkrtz(xr[j].x, xr[j].y);
                    v.y = pkrtz(xr[j].z, xr[j].w);
                    *(uint2*)((char*)Al + ((r * 128 + xr_c * 8) ^ ((r & 7) << 4))) = v;
                }
            }
            #pragma unroll
            for (int j = 0; j < 4; ++j) {
                const int r = j * 32 + xr_r;
                uint2 v;
                v.x = pkrtz(wreg[j].x, wreg[j].y);
                v.y = pkrtz(wreg[j].z, wreg[j].w);
                *(uint2*)((char*)Bl + ((r * 128 + xr_c * 8) ^ ((r & 7) << 4))) = v;
            }
        }
        __syncthreads();

        if (t < 7) {
            const int k0 = (t + 1) * 64;
            if (XF16) {
                const f16* X = (const f16*)Xv;
                #pragma unroll
                for (int j = 0; j < 2; ++j)
                    xh[j] = *(const uint4*)&X[(size_t)(row0 + j * 64 + xh_r) * 512 + k0 + xh_c * 8];
            } else {
                const float* X = (const float*)Xv;
                #pragma unroll
                for (int j = 0; j < 4; ++j)
                    xr[j] = *(const float4*)&X[(size_t)(row0 + j * 32 + xr_r) * 512 + k0 + xr_c * 4];
            }
            #pragma unroll
            for (int j = 0; j < 4; ++j)
                wreg[j] = *(const float4*)&W[(size_t)(col0 + j * 32 + xr_r) * 512 + k0 + xr_c * 4];
        }

        const int ra0 = wr * 64 + lq;
        const int ra1 = wr * 64 + 32 + lq;
        const int rbc = wc * 32 + lq;
        #pragma unroll
        for (int ks = 0; ks < 4; ++ks) {
            const unsigned koff = ks * 32 + half_ * 16;
            f16x8 a0, a1, bf;
            if (TRANSOUT) {
                a0 = *(const f16x8*)((char*)Bl + ((ra0 * 128 + koff) ^ ((ra0 & 7) << 4)));
                a1 = *(const f16x8*)((char*)Bl + ((ra1 * 128 + koff) ^ ((ra1 & 7) << 4)));
                bf = *(const f16x8*)((char*)Al + ((rbc * 128 + koff) ^ ((rbc & 7) << 4)));
            } else {
                a0 = *(const f16x8*)((char*)Al + ((ra0 * 128 + koff) ^ ((ra0 & 7) << 4)));
                a1 = *(const f16x8*)((char*)Al + ((ra1 * 128 + koff) ^ ((ra1 & 7) << 4)));
                bf = *(const f16x8*)((char*)Bl + ((rbc * 128 + koff) ^ ((rbc & 7) << 4)));
            }
            acc[0] = __builtin_amdgcn_mfma_f32_32x32x16_f16(a0, bf, acc[0], 0, 0, 0);
            acc[1] = __builtin_amdgcn_mfma_f32_32x32x16_f16(a1, bf, acc[1], 0, 0, 0);
        }
    }

    if (TRANSOUT) {
        const int lg = row0 + wc * 32 + lq;
        const int bI = lg >> 9, ll = lg & 511;
        #pragma unroll
        for (int rs = 0; rs < 2; ++rs) {
            #pragma unroll
            for (int r = 0; r < 16; ++r) {
                const int n = col0 + wr * 64 + rs * 32 + (r & 3) + 8 * (r >> 2) + 4 * half_;
                const float v = acc[rs][r] + bias[n];
                ((f16*)Yv)[((size_t)(bI * 512 + n)) * 512 + ll] = (f16)v;
            }
        }
    } else {
        const float bv = bias[col0 + wc * 32 + lq];
        #pragma unroll
        for (int rs = 0; rs < 2; ++rs) {
            #pragma unroll
            for (int r = 0; r < 16; ++r) {
                const int row = row0 + wr * 64 + rs * 32 + (r & 3) + 8 * (r >> 2) + 4 * half_;
                const float v = acc[rs][r] + bv;
                const size_t off = (size_t)row * 512 + col0 + wc * 32 + lq;
                if (OUTF32) ((float*)Yv)[off] = v;
                else        ((f16*)Yv)[off]   = (f16)v;
            }
        }
    }
}

__global__ __launch_bounds__(512) void gemm_qkv(
    const float* __restrict__ query, const float* __restrict__ key,
    const float* __restrict__ value,
    const float* __restrict__ Wq, const float* __restrict__ bq,
    const float* __restrict__ Wk, const float* __restrict__ bk,
    const float* __restrict__ Wv, const float* __restrict__ bv,
    void* __restrict__ Qb, void* __restrict__ Kb, void* __restrict__ VT)
{
    __shared__ f16 lds[2 * 128 * 64];
    const int wg  = blockIdx.x;
    const int xcd = wg & 7;
    const int i   = wg >> 3;
    const int col = i & 3;
    const int p   = i >> 2;
    const int pg  = xcd * 24 + p;       // 0..191
    const int z   = pg >> 6;
    const int y   = pg & 63;
    const int row0 = y * 128, col0 = col * 128;

    if (z == 0)      gemm_core<0, 0, 0>(query, Wq, bq, Qb, row0, col0, lds);
    else if (z == 1) gemm_core<0, 0, 0>(key,   Wk, bk, Kb, row0, col0, lds);
    else             gemm_core<0, 0, 1>(value, Wv, bv, VT, row0, col0, lds);
}

__global__ __launch_bounds__(512) void gemm_o(
    const void* __restrict__ X, const float* __restrict__ Wo,
    const float* __restrict__ bo, void* __restrict__ Y)
{
    __shared__ f16 lds[2 * 128 * 64];
    const int wg  = blockIdx.x;
    const int xcd = wg & 7;
    const int i   = wg >> 3;
    const int col = i & 3;
    const int y   = xcd * 8 + (i >> 2);
    gemm_core<1, 1, 0>(X, Wo, bo, Y, y * 128, col * 128, lds);
}

// ---------------------------------------------------------------------------
// 1-wave flash attention, K/V double-buffered in LDS via global_load_lds.
// LDS linear (instr writes base+lane*16); global SOURCE pre-swizzled per lane
// (chunk ^= row&7); fragment ds_reads apply the same XOR (4-way conflicts max).
// Counted waits: tile t+1's 16 loads stay in flight across tile t's compute;
// s_waitcnt vmcnt(16) drains only tile t's.  No barriers (single wave).
// ---------------------------------------------------------------------------
__global__ __launch_bounds__(64) void attn_kernel(
    const f16* __restrict__ Q, const f16* __restrict__ K,
    const f16* __restrict__ VT, const float* __restrict__ Wg,
    const float* __restrict__ bg, const float* __restrict__ lam1,
    f16* __restrict__ ATT)
{
    __shared__ f16 Kl[2][64 * 64];   // 2 x 8KB
    __shared__ f16 Vl[2][64 * 64];   // 2 x 8KB

    const int lane = threadIdx.x;     // 0..63
    const int lq   = lane & 31;
    const int half = lane >> 5;
    const int bh   = blockIdx.x;      // same bh -> same XCD
    const int b    = bh >> 3;
    const int h    = bh & 7;
    const int q0w  = blockIdx.y * 32;
    const int q    = q0w + lq;

    const int srow   = lane >> 3;               // 0..7 (row within 8-row group)
    const int schunk = lane & 7;                // LDS chunk this lane fills
    const int gchunk = schunk ^ (srow & 7);     // pre-swizzled source chunk

    const float sg  = 1.f / (1.f + __expf(-lam1[0]));
    const float osg = 1.f - sg;

    // Q fragments (B-operand)
    f16x8 qh[4];
    {
        const f16* qrow = Q + ((size_t)(b * L_ + q) * DM_ + h * DK_);
        #pragma unroll
        for (int db = 0; db < 4; ++db)
            qh[db] = *(const f16x8*)&qrow[db * 16 + 8 * half];
    }

    // fused gamma: g = q_row . Wg^T + bg ; qp = (|g|+1)^-2
    float A0, A1, qpw;
    {
        float g0 = 0.f, g1 = 0.f;
        #pragma unroll
        for (int db = 0; db < 4; ++db)
            #pragma unroll
            for (int j = 0; j < 8; ++j) {
                const int d = db * 16 + 8 * half + j;
                const float qv = (float)qh[db][j];
                g0 = fmaf(qv, Wg[d], g0);
                g1 = fmaf(qv, Wg[64 + d], g1);
            }
        g0 += __shfl_xor(g0, 32);
        g1 += __shfl_xor(g1, 32);
        g0 += bg[0];
        g1 += bg[1];
        const float t0 = fabsf(g0) + 1.f, t1 = fabsf(g1) + 1.f;
        const float p0 = 1.f / (t0 * t0), p1 = 1.f / (t1 * t1);
        A0 = -NLOG2E_H_ * p0;       // c >= q (triu)
        A1 = -NLOG2E_H_ * p1;       // c <  q (tril)
        float mn = NLOG2E_H_ * fminf(p0, p1);
        #pragma unroll
        for (int off = 1; off < 64; off <<= 1) mn = fminf(mn, __shfl_xor(mn, off));
        qpw = mn;
    }

    f32x16 aS0, aS1, aA0, aA1;
    #pragma unroll
    for (int i = 0; i < 16; ++i) { aS0[i] = 0.f; aS1[i] = 0.f; aA0[i] = 0.f; aA1[i] = 0.f; }
    float m2 = -3.0e38f, sumS = 0.f, sumA = 0.f;

    const f16* Kbase = K  + ((size_t)(b * L_) * DM_ + h * DK_);
    const f16* Vbase = VT + ((size_t)(b * DM_ + h * DK_) * L_);

    // prologue: stage tile 0 -> buffer 0 (16 async loads, no VGPR cost)
    #pragma unroll
    for (int p = 0; p < 8; ++p) {
        gl_lds16(&Kbase[(size_t)(p * 8 + srow) * DM_ + gchunk * 8], &Kl[0][p * 512]);
        gl_lds16(&Vbase[(size_t)(p * 8 + srow) * L_  + gchunk * 8], &Vl[0][p * 512]);
    }

    #pragma unroll
    for (int t = 0; t < 8; ++t) {
        const int c0 = t * 64;
        const f16* Kc = Kl[t & 1];
        const f16* Vc = Vl[t & 1];

        if (t < 7) {
            const int c1 = c0 + 64;
            f16* Kn = Kl[(t + 1) & 1];
            f16* Vn = Vl[(t + 1) & 1];
            #pragma unroll
            for (int p = 0; p < 8; ++p) {
                gl_lds16(&Kbase[(size_t)(c1 + p * 8 + srow) * DM_ + gchunk * 8], &Kn[p * 512]);
                gl_lds16(&Vbase[(size_t)(p * 8 + srow) * L_ + c1 + gchunk * 8], &Vn[p * 512]);
            }
            asm volatile("s_waitcnt vmcnt(16)" ::: "memory");   // drain tile t only
        } else {
            asm volatile("s_waitcnt vmcnt(0)" ::: "memory");
        }
        __builtin_amdgcn_sched_barrier(0);

        // fragment reads (swizzled; (32+lq)&7 == lq&7)
        f16x8 ka[4], kb2[4], vfa[4], vfb[4];
        #pragma unroll
        for (int db = 0; db < 4; ++db) {
            const int g = db * 2 + half;
            const int co = (g ^ (lq & 7)) << 3;
            ka[db]  = *(const f16x8*)&Kc[lq * 64 + co];
            kb2[db] = *(const f16x8*)&Kc[(32 + lq) * 64 + co];
            vfa[db] = *(const f16x8*)&Vc[lq * 64 + co];
            vfb[db] = *(const f16x8*)&Vc[(32 + lq) * 64 + co];
        }

        // S^T = K . Q^T
        f32x16 s2a, s2b;
        #pragma unroll
        for (int i = 0; i < 16; ++i) { s2a[i] = 0.f; s2b[i] = 0.f; }
        #pragma unroll
        for (int db = 0; db < 4; ++db) {
            s2a = __builtin_amdgcn_mfma_f32_32x32x16_f16(ka[db],  qh[db], s2a, 0, 0, 0);
            s2b = __builtin_amdgcn_mfma_f32_32x32x16_f16(kb2[db], qh[db], s2b, 0, 0, 0);
        }

        // online max with skip-rescale
        float tm = s2a[0];
        #pragma unroll
        for (int i = 1; i < 16; ++i) tm = fmaxf(tm, s2a[i]);
        #pragma unroll
        for (int i = 0; i < 16; ++i) tm = fmaxf(tm, s2b[i]);
        tm = fmaxf(tm, __shfl_xor(tm, 32));
        if (__any(tm > m2)) {
            const float nm = fmaxf(m2, tm);
            const float sc_ = exp2f((m2 - nm) * LOG2E_);
            m2 = nm;
            sumS *= sc_;
            #pragma unroll
            for (int r = 0; r < 16; ++r) {
                const float s_ = __shfl(sc_, (r & 3) + 8 * (r >> 2) + 4 * half);
                aS0[r] *= s_;
                aS1[r] *= s_;
            }
        }

        // P: exp, pack, permlane-swap into A-fragments, PV MFMAs
        const float nmL = m2 * LOG2E_;
        #pragma unroll
        for (int sub = 0; sub < 2; ++sub) {
            const f32x16& s2 = sub ? s2b : s2a;
            #pragma unroll
            for (int ksl = 0; ksl < 2; ++ksl) {
                const int rb = ksl * 8;
                float p[8];
                #pragma unroll
                for (int rr = 0; rr < 8; ++rr) {
                    p[rr] = exp2f(fmaf(s2[rb + rr], LOG2E_, -nmL));
                    sumS += p[rr];
                }
                union { unsigned u[4]; f16x8 v; } f;
                f.u[0] = pkrtz(p[0], p[1]);
                f.u[1] = pkrtz(p[2], p[3]);
                f.u[2] = pkrtz(p[4], p[5]);
                f.u[3] = pkrtz(p[6], p[7]);
                plswap(f.u[0], f.u[2]);
                plswap(f.u[1], f.u[3]);
                const int ks = sub * 2 + ksl;
                aS0 = __builtin_amdgcn_mfma_f32_32x32x16_f16(f.v, vfa[ks], aS0, 0, 0, 0);
                aS1 = __builtin_amdgcn_mfma_f32_32x32x16_f16(f.v, vfb[ks], aS1, 0, 0, 0);
            }
        }

        // adjacency branch (band-skip far tiles; diagonal tile never skipped)
        int gl_ = q0w - (c0 + 63);
        int gh_ = c0 - (q0w + 31);
        int dmin = gl_ > gh_ ? gl_ : gh_;
        if (dmin < 0) dmin = 0;
        if (qpw * (float)(dmin * dmin) < 40.0f) {
            #pragma unroll
            for (int sub = 0; sub < 2; ++sub) {
                #pragma unroll
                for (int ksl = 0; ksl < 2; ++ksl) {
                    float a[8];
                    #pragma unroll
                    for (int rr = 0; rr < 8; ++rr) {
                        const int kk = (rr & 3) + 8 * (rr >> 2) + 16 * ksl + 4 * half;
                        const int diff = q - (c0 + sub * 32 + kk);
                        const float fd = (float)diff;
                        const float coef = diff > 0 ? A1 : A0;
                        a[rr] = exp2f(coef * fd * fd);
                        sumA += a[rr];
                    }
                    union { unsigned u[4]; f16x8 v; } f;
                    f.u[0] = pkrtz(a[0], a[1]);
                    f.u[1] = pkrtz(a[2], a[3]);
                    f.u[2] = pkrtz(a[4], a[5]);
                    f.u[3] = pkrtz(a[6], a[7]);
                    plswap(f.u[0], f.u[2]);
                    plswap(f.u[1], f.u[3]);
                    const int ks = sub * 2 + ksl;
                    aA0 = __builtin_amdgcn_mfma_f32_32x32x16_f16(f.v, vfa[ks], aA0, 0, 0, 0);
                    aA1 = __builtin_amdgcn_mfma_f32_32x32x16_f16(f.v, vfb[ks], aA1, 0, 0, 0);
                }
            }
        }
    }

    // epilogue: mix branches, degree-normalize, store
    const float St = sumS + __shfl_xor(sumS, 32);
    const float At = sumA + __shfl_xor(sumA, 32);
    const float den = sg * St + osg * At + 1e-9f;
    #pragma unroll
    for (int r = 0; r < 16; ++r) {
        const int row = (r & 3) + 8 * (r >> 2) + 4 * half;
        const float dn = __shfl(den, row);
        const float o0 = (sg * aS0[r] + osg * aA0[r]) / dn;
        const float o1 = (sg * aS1[r] + osg * aA1[r]) / dn;
        const size_t base = (size_t)(b * L_ + q0w + row) * DM_ + h * DK_;
        ATT[base + lq]      = (f16)o0;
        ATT[base + 32 + lq] = (f16)o1;
    }
}

// ---------------------------------------------------------------------------
extern "C" void kernel_launch(void* const* d_in, const int* in_sizes, int n_in,
                              void* d_out, int out_size, void* d_ws, size_t ws_size,
                              hipStream_t stream)
{
    (void)in_sizes; (void)n_in; (void)out_size; (void)ws_size;
    const float* query = (const float*)d_in[0];
    const float* key   = (const float*)d_in[1];
    const float* value = (const float*)d_in[2];
    const float* Wq = (const float*)d_in[3];  const float* bq = (const float*)d_in[4];
    const float* Wk = (const float*)d_in[5];  const float* bk = (const float*)d_in[6];
    const float* Wv = (const float*)d_in[7];  const float* bv = (const float*)d_in[8];
    const float* Wg = (const float*)d_in[9];  const float* bg = (const float*)d_in[10];
    const float* lam1 = (const float*)d_in[11];
    const float* Wo = (const float*)d_in[12]; const float* bo = (const float*)d_in[13];

    f16* ws16 = (f16*)d_ws;
    const size_t NR = (size_t)B_ * L_ * DM_;
    f16* Kb  = ws16;
    f16* VTb = ws16 + NR;
    f16* Qb  = ws16 + 2 * NR;
    f16* ATTb = Qb;   // safe alias: each wave reads exactly the Q cells it later writes

    gemm_qkv<<<768, 512, 0, stream>>>(query, key, value, Wq, bq, Wk, bk, Wv, bv,
                                      Qb, Kb, VTb);

    dim3 ga(H_ * B_, L_ / 32);    // (128, 16), 64 threads = 1 wave per block
    attn_kernel<<<ga, 64, 0, stream>>>(Qb, Kb, VTb, Wg, bg, lam1, ATTb);

    gemm_o<<<256, 512, 0, stream>>>(Qb, Wo, bo, (float*)d_out);
}

// Round 15
// 93.420 us; speedup vs baseline: 2.0253x; 1.0657x over previous
//
#include <hip/hip_runtime.h>
#include <hip/hip_fp16.h>
#include <math.h>

#define B_  16
#define H_  8
#define L_  512
#define DM_ 512
#define DK_ 64
#define LOG2E_ 1.44269504088896340736f
#define NLOG2E_H_ 0.72134752044f   // 0.5 * log2(e)

typedef _Float16 f16;
typedef __attribute__((ext_vector_type(2)))  __fp16   fp16v2;
typedef __attribute__((ext_vector_type(8)))  _Float16 f16x8;
typedef __attribute__((ext_vector_type(16))) float f32x16;

__device__ __forceinline__ unsigned pkrtz(float a, float b) {
    union { fp16v2 v; unsigned u; } cv;
    cv.v = __builtin_amdgcn_cvt_pkrtz(a, b);
    return cv.u;
}
// v_permlane32_swap_b32: x[lanes 32..63] <-> y[lanes 0..31]
__device__ __forceinline__ void plswap(unsigned &x, unsigned &y) {
    asm("v_permlane32_swap_b32 %0, %1" : "+v"(x), "+v"(y));
}

// ---------------------------------------------------------------------------
// W pre-pack: fp32 W[512][512] -> fp16 in MFMA FRAGMENT ORDER:
//   Wpk[nb(16)][ks(32)][half(2)][lane(32)][e(8)],  value = W[nb*32+lane][ks*16+half*8+e]
// Inner-loop fragment load becomes 32 lanes x 16B = 512B contiguous.
// Same fragment layout serves A- and B-operands.  4 matrices (q,k,v,o).
// ---------------------------------------------------------------------------
__global__ __launch_bounds__(256) void convw_pack(
    const float* __restrict__ Wq, const float* __restrict__ Wk,
    const float* __restrict__ Wv, const float* __restrict__ Wo,
    f16* __restrict__ Wpk)
{
    const float* src[4] = {Wq, Wk, Wv, Wo};
    const int t = blockIdx.x * 256 + threadIdx.x;   // 0..131071
    const int m    = t >> 15;
    const int r    = t & 32767;
    const int lane = r & 31;
    const int hf   = (r >> 5) & 1;
    const int ks   = (r >> 6) & 31;
    const int nb   = r >> 11;
    const float* p = src[m] + (size_t)(nb * 32 + lane) * 512 + ks * 16 + hf * 8;
    float4 x0 = *(const float4*)(p);
    float4 x1 = *(const float4*)(p + 4);
    uint4 v;
    v.x = pkrtz(x0.x, x0.y); v.y = pkrtz(x0.z, x0.w);
    v.z = pkrtz(x1.x, x1.y); v.w = pkrtz(x1.z, x1.w);
    *(uint4*)&Wpk[(size_t)m * 262144 + (size_t)r * 8] = v;
}

// ---------------------------------------------------------------------------
// Stream GEMM core:  Y = X[rows,512] @ W^T + bias   (W pre-packed = Wpk_m)
// 32-row X panel staged to LDS ONCE (1 barrier); W fragments streamed
// global->VGPR, fully coalesced (512B/instr).  No per-K-step barriers.
// Wave w covers cols [col0 + w*NT*32, +NT*32).
// TRANSOUT: swapped operands -> C^T, store VT[(b*512+n)][l].
// ---------------------------------------------------------------------------
template<int XF16, int OUTF32, int TRANSOUT, int NWAVES, int NT>
__device__ __forceinline__ void gemm_stream_core(
    const void* __restrict__ Xv, const f16* __restrict__ Wpk_m,
    const float* __restrict__ bias, void* __restrict__ Yv,
    int row0, int col0, f16* Xl)
{
    const int tid   = threadIdx.x;
    const int w     = tid >> 6;
    const int lane  = tid & 63;
    const int lq    = lane & 31;
    const int half_ = lane >> 5;
    const int colw  = col0 + w * (NT * 32);

    // ---- stage X panel once (swizzled) ----
    {
        constexpr int TPR = NWAVES * 64 / 32;   // threads per row
        constexpr int FPT = 512 / TPR;          // f16 per thread
        const int r = tid / TPR, s = tid % TPR;
        const unsigned swz = (r & 7) << 4;
        if (XF16) {
            const f16* X = (const f16*)Xv + (size_t)(row0 + r) * 512 + s * FPT;
            #pragma unroll
            for (int j = 0; j < FPT / 8; ++j) {
                uint4 v = *(const uint4*)(X + j * 8);
                *(uint4*)((char*)Xl + ((r * 1024 + s * FPT * 2 + j * 16) ^ swz)) = v;
            }
        } else {
            const float* X = (const float*)Xv + (size_t)(row0 + r) * 512 + s * FPT;
            #pragma unroll
            for (int j = 0; j < FPT / 8; ++j) {
                float4 x0 = *(const float4*)(X + j * 8);
                float4 x1 = *(const float4*)(X + j * 8 + 4);
                uint4 v;
                v.x = pkrtz(x0.x, x0.y); v.y = pkrtz(x0.z, x0.w);
                v.z = pkrtz(x1.x, x1.y); v.w = pkrtz(x1.z, x1.w);
                *(uint4*)((char*)Xl + ((r * 1024 + s * FPT * 2 + j * 16) ^ swz)) = v;
            }
        }
    }
    __syncthreads();

    // ---- K-loop: LDS a-frag + coalesced streamed W-frags -> MFMA ----
    f32x16 acc[NT];
    #pragma unroll
    for (int nt = 0; nt < NT; ++nt)
        #pragma unroll
        for (int i = 0; i < 16; ++i) acc[nt][i] = 0.f;

    const f16* wp[NT];
    #pragma unroll
    for (int nt = 0; nt < NT; ++nt)
        wp[nt] = Wpk_m + ((size_t)((colw / 32 + nt) * 64 + half_)) * 256 + lq * 8;

    const unsigned aswz = (lq & 7) << 4;

    #pragma unroll 4
    for (int ks = 0; ks < 32; ++ks) {
        f16x8 a = *(const f16x8*)((char*)Xl + ((lq * 1024 + ks * 32 + half_ * 16) ^ aswz));
        f16x8 bfr[NT];
        #pragma unroll
        for (int nt = 0; nt < NT; ++nt)
            bfr[nt] = *(const f16x8*)(wp[nt] + (size_t)ks * 512);
        #pragma unroll
        for (int nt = 0; nt < NT; ++nt) {
            if (TRANSOUT)
                acc[nt] = __builtin_amdgcn_mfma_f32_32x32x16_f16(bfr[nt], a, acc[nt], 0, 0, 0);
            else
                acc[nt] = __builtin_amdgcn_mfma_f32_32x32x16_f16(a, bfr[nt], acc[nt], 0, 0, 0);
        }
    }

    // ---- epilogue ----
    if (TRANSOUT) {
        const int lg = row0 + lq;
        const int bI = lg >> 9, ll = lg & 511;
        #pragma unroll
        for (int nt = 0; nt < NT; ++nt)
            #pragma unroll
            for (int r = 0; r < 16; ++r) {
                const int n = colw + nt * 32 + (r & 3) + 8 * (r >> 2) + 4 * half_;
                const float v = acc[nt][r] + bias[n];
                ((f16*)Yv)[((size_t)(bI * 512 + n)) * 512 + ll] = (f16)v;
            }
    } else {
        #pragma unroll
        for (int nt = 0; nt < NT; ++nt) {
            const float bv = bias[colw + nt * 32 + lq];
            #pragma unroll
            for (int r = 0; r < 16; ++r) {
                const int row = row0 + (r & 3) + 8 * (r >> 2) + 4 * half_;
                const float v = acc[nt][r] + bv;
                const size_t off = (size_t)row * 512 + colw + nt * 32 + lq;
                if (OUTF32) ((float*)Yv)[off] = v;
                else        ((f16*)Yv)[off]   = (f16)v;
            }
        }
    }
}

// fused Q/K/V projections: 768 blocks x 512 thr (8 waves), XCD-chunked.
// xcd = wg&7; i = wg>>3 (0..95); pg = xcd*96+i (0..767); z = pg>>8; y = pg&255.
__global__ __launch_bounds__(512) void gemm_qkv(
    const float* __restrict__ query, const float* __restrict__ key,
    const float* __restrict__ value, const f16* __restrict__ Wpk,
    const float* __restrict__ bq, const float* __restrict__ bk,
    const float* __restrict__ bv,
    void* __restrict__ Qb, void* __restrict__ Kb, void* __restrict__ VT)
{
    __shared__ f16 Xl[32 * 512];
    const int wg  = blockIdx.x;
    const int xcd = wg & 7;
    const int i   = wg >> 3;
    const int pg  = xcd * 96 + i;       // 0..767
    const int z   = pg >> 8;
    const int y   = pg & 255;
    const int row0 = y * 32;

    if (z == 0)
        gemm_stream_core<0, 0, 0, 8, 2>(query, Wpk,          bq, Qb, row0, 0, Xl);
    else if (z == 1)
        gemm_stream_core<0, 0, 0, 8, 2>(key,   Wpk + 262144, bk, Kb, row0, 0, Xl);
    else
        gemm_stream_core<0, 0, 1, 8, 2>(value, Wpk + 524288, bv, VT, row0, 0, Xl);
}

// output GEMM: 512 blocks x 256 thr (4 waves), XCD-chunked, col-split x2.
// xcd = wg&7; i = wg>>3 (0..63); pg = xcd*64+i; cb = pg&1; y = pg>>1.
__global__ __launch_bounds__(256) void gemm_o(
    const void* __restrict__ X, const f16* __restrict__ Wpk,
    const float* __restrict__ bo, void* __restrict__ Y)
{
    __shared__ f16 Xl[32 * 512];
    const int wg  = blockIdx.x;
    const int xcd = wg & 7;
    const int i   = wg >> 3;
    const int pg  = xcd * 64 + i;       // 0..511
    const int cb  = pg & 1;
    const int y   = pg >> 1;
    gemm_stream_core<1, 1, 0, 4, 2>(X, Wpk + 786432, bo, Y, y * 32, cb * 256, Xl);
}

// ---------------------------------------------------------------------------
// ZERO-LDS MFMA flash attention (R6, best measured: 42.9 us).  One wave per
// block; K fragments = rows of K; V fragments = rows of pre-transposed VT;
// loaded straight global->VGPR.  Broadcasts via __shfl; no barriers.
// ---------------------------------------------------------------------------
__global__ __launch_bounds__(64) void attn_kernel(
    const f16* __restrict__ Q, const f16* __restrict__ K,
    const f16* __restrict__ VT, const float* __restrict__ Wg,
    const float* __restrict__ bg, const float* __restrict__ lam1,
    f16* __restrict__ ATT)
{
    const int lane = threadIdx.x;     // 0..63
    const int lq   = lane & 31;
    const int half = lane >> 5;
    const int bh   = blockIdx.x;      // same bh -> same XCD
    const int b    = bh >> 3;
    const int h    = bh & 7;
    const int q0w  = blockIdx.y * 32;
    const int q    = q0w + lq;

    const float sg  = 1.f / (1.f + __expf(-lam1[0]));
    const float osg = 1.f - sg;

    // Q fragments (B-operand)
    f16x8 qh[4];
    {
        const f16* qrow = Q + ((size_t)(b * L_ + q) * DM_ + h * DK_);
        #pragma unroll
        for (int db = 0; db < 4; ++db)
            qh[db] = *(const f16x8*)&qrow[db * 16 + 8 * half];
    }

    // fused gamma: g = q_row . Wg^T + bg ; qp = (|g|+1)^-2
    float A0, A1, qpw;
    {
        float g0 = 0.f, g1 = 0.f;
        #pragma unroll
        for (int db = 0; db < 4; ++db)
            #pragma unroll
            for (int j = 0; j < 8; ++j) {
                const int d = db * 16 + 8 * half + j;
                const float qv = (float)qh[db][j];
                g0 = fmaf(qv, Wg[d], g0);
                g1 = fmaf(qv, Wg[64 + d], g1);
            }
        g0 += __shfl_xor(g0, 32);
        g1 += __shfl_xor(g1, 32);
        g0 += bg[0];
        g1 += bg[1];
        const float t0 = fabsf(g0) + 1.f, t1 = fabsf(g1) + 1.f;
        const float p0 = 1.f / (t0 * t0), p1 = 1.f / (t1 * t1);
        A0 = -NLOG2E_H_ * p0;       // c >= q (triu)
        A1 = -NLOG2E_H_ * p1;       // c <  q (tril)
        float mn = NLOG2E_H_ * fminf(p0, p1);
        #pragma unroll
        for (int off = 1; off < 64; off <<= 1) mn = fminf(mn, __shfl_xor(mn, off));
        qpw = mn;
    }

    f32x16 aS0, aS1, aA0, aA1;
    #pragma unroll
    for (int i = 0; i < 16; ++i) { aS0[i] = 0.f; aS1[i] = 0.f; aA0[i] = 0.f; aA1[i] = 0.f; }
    float m2 = -3.0e38f, sumS = 0.f, sumA = 0.f;

    const f16* Kbase = K  + ((size_t)(b * L_) * DM_ + h * DK_);
    const f16* Vbase = VT + ((size_t)(b * DM_ + h * DK_) * L_);

    for (int t = 0; t < 8; ++t) {
        const int c0 = t * 64;

        f16x8 ka[4], kb2[4], vfa[4], vfb[4];
        #pragma unroll
        for (int db = 0; db < 4; ++db) {
            const int dof = db * 16 + 8 * half;
            ka[db]  = *(const f16x8*)&Kbase[(size_t)(c0 + lq) * DM_ + dof];
            kb2[db] = *(const f16x8*)&Kbase[(size_t)(c0 + 32 + lq) * DM_ + dof];
        }
        #pragma unroll
        for (int ks = 0; ks < 4; ++ks) {
            const int coff = c0 + ks * 16 + 8 * half;
            vfa[ks] = *(const f16x8*)&Vbase[(size_t)lq * L_ + coff];
            vfb[ks] = *(const f16x8*)&Vbase[(size_t)(32 + lq) * L_ + coff];
        }

        // S^T = K . Q^T
        f32x16 s2a, s2b;
        #pragma unroll
        for (int i = 0; i < 16; ++i) { s2a[i] = 0.f; s2b[i] = 0.f; }
        #pragma unroll
        for (int db = 0; db < 4; ++db) {
            s2a = __builtin_amdgcn_mfma_f32_32x32x16_f16(ka[db],  qh[db], s2a, 0, 0, 0);
            s2b = __builtin_amdgcn_mfma_f32_32x32x16_f16(kb2[db], qh[db], s2b, 0, 0, 0);
        }

        // online max with skip-rescale
        float tm = s2a[0];
        #pragma unroll
        for (int i = 1; i < 16; ++i) tm = fmaxf(tm, s2a[i]);
        #pragma unroll
        for (int i = 0; i < 16; ++i) tm = fmaxf(tm, s2b[i]);
        tm = fmaxf(tm, __shfl_xor(tm, 32));
        if (__any(tm > m2)) {
            const float nm = fmaxf(m2, tm);
            const float sc = exp2f((m2 - nm) * LOG2E_);
            m2 = nm;
            sumS *= sc;
            #pragma unroll
            for (int r = 0; r < 16; ++r) {
                const float s_ = __shfl(sc, (r & 3) + 8 * (r >> 2) + 4 * half);
                aS0[r] *= s_;
                aS1[r] *= s_;
            }
        }

        // P: exp, pack, permlane-swap into A-fragments, PV MFMAs
        const float nmL = m2 * LOG2E_;
        #pragma unroll
        for (int sub = 0; sub < 2; ++sub) {
            const f32x16& s2 = sub ? s2b : s2a;
            #pragma unroll
            for (int ksl = 0; ksl < 2; ++ksl) {
                const int rb = ksl * 8;
                float p[8];
                #pragma unroll
                for (int rr = 0; rr < 8; ++rr) {
                    p[rr] = exp2f(fmaf(s2[rb + rr], LOG2E_, -nmL));
                    sumS += p[rr];
                }
                union { unsigned u[4]; f16x8 v; } f;
                f.u[0] = pkrtz(p[0], p[1]);
                f.u[1] = pkrtz(p[2], p[3]);
                f.u[2] = pkrtz(p[4], p[5]);
                f.u[3] = pkrtz(p[6], p[7]);
                plswap(f.u[0], f.u[2]);
                plswap(f.u[1], f.u[3]);
                const int ks = sub * 2 + ksl;
                aS0 = __builtin_amdgcn_mfma_f32_32x32x16_f16(f.v, vfa[ks], aS0, 0, 0, 0);
                aS1 = __builtin_amdgcn_mfma_f32_32x32x16_f16(f.v, vfb[ks], aS1, 0, 0, 0);
            }
        }

        // adjacency branch (band-skip far tiles; diagonal tile never skipped)
        int gl_ = q0w - (c0 + 63);
        int gh_ = c0 - (q0w + 31);
        int dmin = gl_ > gh_ ? gl_ : gh_;
        if (dmin < 0) dmin = 0;
        if (qpw * (float)(dmin * dmin) < 40.0f) {
            #pragma unroll
            for (int sub = 0; sub < 2; ++sub) {
                #pragma unroll
                for (int ksl = 0; ksl < 2; ++ksl) {
                    float a[8];
                    #pragma unroll
                    for (int rr = 0; rr < 8; ++rr) {
                        const int kk = (rr & 3) + 8 * (rr >> 2) + 16 * ksl + 4 * half;
                        const int diff = q - (c0 + sub * 32 + kk);
                        const float fd = (float)diff;
                        const float coef = diff > 0 ? A1 : A0;
                        a[rr] = exp2f(coef * fd * fd);
                        sumA += a[rr];
                    }
                    union { unsigned u[4]; f16x8 v; } f;
                    f.u[0] = pkrtz(a[0], a[1]);
                    f.u[1] = pkrtz(a[2], a[3]);
                    f.u[2] = pkrtz(a[4], a[5]);
                    f.u[3] = pkrtz(a[6], a[7]);
                    plswap(f.u[0], f.u[2]);
                    plswap(f.u[1], f.u[3]);
                    const int ks = sub * 2 + ksl;
                    aA0 = __builtin_amdgcn_mfma_f32_32x32x16_f16(f.v, vfa[ks], aA0, 0, 0, 0);
                    aA1 = __builtin_amdgcn_mfma_f32_32x32x16_f16(f.v, vfb[ks], aA1, 0, 0, 0);
                }
            }
        }
    }

    // epilogue: mix branches, degree-normalize, store
    const float St = sumS + __shfl_xor(sumS, 32);
    const float At = sumA + __shfl_xor(sumA, 32);
    const float den = sg * St + osg * At + 1e-9f;
    #pragma unroll
    for (int r = 0; r < 16; ++r) {
        const int row = (r & 3) + 8 * (r >> 2) + 4 * half;
        const float dn = __shfl(den, row);
        const float o0 = (sg * aS0[r] + osg * aA0[r]) / dn;
        const float o1 = (sg * aS1[r] + osg * aA1[r]) / dn;
        const size_t base = (size_t)(b * L_ + q0w + row) * DM_ + h * DK_;
        ATT[base + lq]      = (f16)o0;
        ATT[base + 32 + lq] = (f16)o1;
    }
}

// ---------------------------------------------------------------------------
extern "C" void kernel_launch(void* const* d_in, const int* in_sizes, int n_in,
                              void* d_out, int out_size, void* d_ws, size_t ws_size,
                              hipStream_t stream)
{
    (void)in_sizes; (void)n_in; (void)out_size; (void)ws_size;
    const float* query = (const float*)d_in[0];
    const float* key   = (const float*)d_in[1];
    const float* value = (const float*)d_in[2];
    const float* Wq = (const float*)d_in[3];  const float* bq = (const float*)d_in[4];
    const float* Wk = (const float*)d_in[5];  const float* bk = (const float*)d_in[6];
    const float* Wv = (const float*)d_in[7];  const float* bv = (const float*)d_in[8];
    const float* Wg = (const float*)d_in[9];  const float* bg = (const float*)d_in[10];
    const float* lam1 = (const float*)d_in[11];
    const float* Wo = (const float*)d_in[12]; const float* bo = (const float*)d_in[13];

    f16* ws16 = (f16*)d_ws;
    const size_t NR = (size_t)B_ * L_ * DM_;      // 4 Mi elements
    f16* Kb   = ws16;
    f16* VTb  = ws16 + NR;
    f16* Qb   = ws16 + 2 * NR;
    f16* Wpkb = ws16 + 3 * NR;                    // 4 x 262144 f16 = 2 MB
    f16* ATTb = Qb;   // safe alias: each wave reads exactly the Q cells it later writes

    convw_pack<<<512, 256, 0, stream>>>(Wq, Wk, Wv, Wo, Wpkb);

    gemm_qkv<<<768, 512, 0, stream>>>(query, key, value, Wpkb, bq, bk, bv,
                                      Qb, Kb, VTb);

    dim3 ga(H_ * B_, L_ / 32);    // (128, 16), 64 threads = 1 wave per block
    attn_kernel<<<ga, 64, 0, stream>>>(Qb, Kb, VTb, Wg, bg, lam1, ATTb);

    gemm_o<<<512, 256, 0, stream>>>(Qb, Wpkb, bo, (float*)d_out);
}

// Round 16
// 91.311 us; speedup vs baseline: 2.0721x; 1.0231x over previous
//
#include <hip/hip_runtime.h>
#include <hip/hip_fp16.h>
#include <math.h>

#define B_  16
#define H_  8
#define L_  512
#define DM_ 512
#define DK_ 64
#define LOG2E_ 1.44269504088896340736f
#define NLOG2E_H_ 0.72134752044f   // 0.5 * log2(e)

typedef _Float16 f16;
typedef __attribute__((ext_vector_type(2)))  __fp16   fp16v2;
typedef __attribute__((ext_vector_type(8)))  _Float16 f16x8;
typedef __attribute__((ext_vector_type(16))) float f32x16;

__device__ __forceinline__ unsigned pkrtz(float a, float b) {
    union { fp16v2 v; unsigned u; } cv;
    cv.v = __builtin_amdgcn_cvt_pkrtz(a, b);
    return cv.u;
}
// v_permlane32_swap_b32: x[lanes 32..63] <-> y[lanes 0..31]
__device__ __forceinline__ void plswap(unsigned &x, unsigned &y) {
    asm("v_permlane32_swap_b32 %0, %1" : "+v"(x), "+v"(y));
}

// ---------------------------------------------------------------------------
// W pre-pack (unchanged from R15): Wpk[nb][ks][hf][lane][8].
// ---------------------------------------------------------------------------
__global__ __launch_bounds__(256) void convw_pack(
    const float* __restrict__ Wq, const float* __restrict__ Wk,
    const float* __restrict__ Wv, const float* __restrict__ Wo,
    f16* __restrict__ Wpk)
{
    const float* src[4] = {Wq, Wk, Wv, Wo};
    const int t = blockIdx.x * 256 + threadIdx.x;
    const int m    = t >> 15;
    const int r    = t & 32767;
    const int lane = r & 31;
    const int hf   = (r >> 5) & 1;
    const int ks   = (r >> 6) & 31;
    const int nb   = r >> 11;
    const float* p = src[m] + (size_t)(nb * 32 + lane) * 512 + ks * 16 + hf * 8;
    float4 x0 = *(const float4*)(p);
    float4 x1 = *(const float4*)(p + 4);
    uint4 v;
    v.x = pkrtz(x0.x, x0.y); v.y = pkrtz(x0.z, x0.w);
    v.z = pkrtz(x1.x, x1.y); v.w = pkrtz(x1.z, x1.w);
    *(uint4*)&Wpk[(size_t)m * 262144 + (size_t)r * 8] = v;
}

// ---------------------------------------------------------------------------
// Stream GEMM core.  OUTMODE: 0 = row-major Y;  1 = Vpk fragment-pack;
// 2 = Kpk fragment-pack (swapped MFMA orientation).
//   Kpk[(b,h)][cb:16][ks:4][hf:2][ln:32][e:8] = K_head[cb*32+ln][ks*16+hf*8+e]
//   Vpk[(b,h)][t:8][ks:4][d2:2][hf:2][ln:32][e:8] = V^T_head[d2*32+ln][t*64+ks*16+hf*8+e]
// Pack stores are 512B-contiguous per instruction (lq stride 16B, half fills +8B).
// ---------------------------------------------------------------------------
template<int XF16, int OUTF32, int OUTMODE, int NWAVES, int NT>
__device__ __forceinline__ void gemm_stream_core(
    const void* __restrict__ Xv, const f16* __restrict__ Wpk_m,
    const float* __restrict__ bias, void* __restrict__ Yv,
    int row0, int col0, f16* Xl)
{
    const int tid   = threadIdx.x;
    const int w     = tid >> 6;
    const int lane  = tid & 63;
    const int lq    = lane & 31;
    const int half_ = lane >> 5;
    const int colw  = col0 + w * (NT * 32);

    // ---- stage X panel once (swizzled) ----
    {
        constexpr int TPR = NWAVES * 64 / 32;
        constexpr int FPT = 512 / TPR;
        const int r = tid / TPR, s = tid % TPR;
        const unsigned swz = (r & 7) << 4;
        if (XF16) {
            const f16* X = (const f16*)Xv + (size_t)(row0 + r) * 512 + s * FPT;
            #pragma unroll
            for (int j = 0; j < FPT / 8; ++j) {
                uint4 v = *(const uint4*)(X + j * 8);
                *(uint4*)((char*)Xl + ((r * 1024 + s * FPT * 2 + j * 16) ^ swz)) = v;
            }
        } else {
            const float* X = (const float*)Xv + (size_t)(row0 + r) * 512 + s * FPT;
            #pragma unroll
            for (int j = 0; j < FPT / 8; ++j) {
                float4 x0 = *(const float4*)(X + j * 8);
                float4 x1 = *(const float4*)(X + j * 8 + 4);
                uint4 v;
                v.x = pkrtz(x0.x, x0.y); v.y = pkrtz(x0.z, x0.w);
                v.z = pkrtz(x1.x, x1.y); v.w = pkrtz(x1.z, x1.w);
                *(uint4*)((char*)Xl + ((r * 1024 + s * FPT * 2 + j * 16) ^ swz)) = v;
            }
        }
    }
    __syncthreads();

    f32x16 acc[NT];
    #pragma unroll
    for (int nt = 0; nt < NT; ++nt)
        #pragma unroll
        for (int i = 0; i < 16; ++i) acc[nt][i] = 0.f;

    const f16* wp[NT];
    #pragma unroll
    for (int nt = 0; nt < NT; ++nt)
        wp[nt] = Wpk_m + ((size_t)((colw / 32 + nt) * 64 + half_)) * 256 + lq * 8;

    const unsigned aswz = (lq & 7) << 4;

    #pragma unroll 4
    for (int ks = 0; ks < 32; ++ks) {
        f16x8 a = *(const f16x8*)((char*)Xl + ((lq * 1024 + ks * 32 + half_ * 16) ^ aswz));
        f16x8 bfr[NT];
        #pragma unroll
        for (int nt = 0; nt < NT; ++nt)
            bfr[nt] = *(const f16x8*)(wp[nt] + (size_t)ks * 512);
        #pragma unroll
        for (int nt = 0; nt < NT; ++nt) {
            if (OUTMODE == 2)
                acc[nt] = __builtin_amdgcn_mfma_f32_32x32x16_f16(bfr[nt], a, acc[nt], 0, 0, 0);
            else
                acc[nt] = __builtin_amdgcn_mfma_f32_32x32x16_f16(a, bfr[nt], acc[nt], 0, 0, 0);
        }
    }

    // ---- epilogue ----
    if (OUTMODE == 2) {
        // Kpk: acc[nt][r] = K^T frag: n = colw+nt*32+crow(r,half_), c-lane = row0+lq
        const int b  = row0 >> 9;
        const int cb = (row0 >> 5) & 15;
        f16* Kp = (f16*)Yv + (size_t)(b * H_ + w) * 32768;
        #pragma unroll
        for (int nt = 0; nt < NT; ++nt)
            #pragma unroll
            for (int g = 0; g < 4; ++g) {
                const int n0 = w * 64 + nt * 32 + 8 * g + 4 * half_;
                const float4 b4 = *(const float4*)&bias[n0];
                const int ks2 = nt * 2 + (g >> 1);
                uint2 v;
                v.x = pkrtz(acc[nt][4 * g + 0] + b4.x, acc[nt][4 * g + 1] + b4.y);
                v.y = pkrtz(acc[nt][4 * g + 2] + b4.z, acc[nt][4 * g + 3] + b4.w);
                *(uint2*)&Kp[(cb * 4 + ks2) * 512 + (g & 1) * 256 + lq * 8 + half_ * 4] = v;
            }
    } else if (OUTMODE == 1) {
        // Vpk: acc[nt][r] = V[c = row0+crow(r,half_)][d = nt*32+lq]
        const int b  = row0 >> 9;
        const int cB = row0 & 511;
        const int tt = cB >> 6;
        const int kbase = (cB >> 4) & 3;
        f16* Vp = (f16*)Yv + (size_t)(b * H_ + w) * 32768;
        #pragma unroll
        for (int nt = 0; nt < NT; ++nt) {
            const float bv = bias[w * 64 + nt * 32 + lq];
            #pragma unroll
            for (int g = 0; g < 4; ++g) {
                const int ks2 = kbase + (g >> 1);
                uint2 v;
                v.x = pkrtz(acc[nt][4 * g + 0] + bv, acc[nt][4 * g + 1] + bv);
                v.y = pkrtz(acc[nt][4 * g + 2] + bv, acc[nt][4 * g + 3] + bv);
                *(uint2*)&Vp[((tt * 4 + ks2) * 2 + nt) * 512 + (g & 1) * 256 + lq * 8 + half_ * 4] = v;
            }
        }
    } else {
        #pragma unroll
        for (int nt = 0; nt < NT; ++nt) {
            const float bv = bias[colw + nt * 32 + lq];
            #pragma unroll
            for (int r = 0; r < 16; ++r) {
                const int row = row0 + (r & 3) + 8 * (r >> 2) + 4 * half_;
                const float v = acc[nt][r] + bv;
                const size_t off = (size_t)row * 512 + colw + nt * 32 + lq;
                if (OUTF32) ((float*)Yv)[off] = v;
                else        ((f16*)Yv)[off]   = (f16)v;
            }
        }
    }
}

// fused Q/K/V projections: 768 blocks x 512 thr, XCD-chunked (as R15).
__global__ __launch_bounds__(512) void gemm_qkv(
    const float* __restrict__ query, const float* __restrict__ key,
    const float* __restrict__ value, const f16* __restrict__ Wpk,
    const float* __restrict__ bq, const float* __restrict__ bk,
    const float* __restrict__ bv,
    void* __restrict__ Qb, void* __restrict__ Kpk, void* __restrict__ Vpk)
{
    __shared__ f16 Xl[32 * 512];
    const int wg  = blockIdx.x;
    const int xcd = wg & 7;
    const int i   = wg >> 3;
    const int pg  = xcd * 96 + i;       // 0..767
    const int z   = pg >> 8;
    const int y   = pg & 255;
    const int row0 = y * 32;

    if (z == 0)
        gemm_stream_core<0, 0, 0, 8, 2>(query, Wpk,          bq, Qb,  row0, 0, Xl);
    else if (z == 1)
        gemm_stream_core<0, 0, 2, 8, 2>(key,   Wpk + 262144, bk, Kpk, row0, 0, Xl);
    else
        gemm_stream_core<0, 0, 1, 8, 2>(value, Wpk + 524288, bv, Vpk, row0, 0, Xl);
}

// output GEMM: 512 blocks x 256 thr (as R15).
__global__ __launch_bounds__(256) void gemm_o(
    const void* __restrict__ X, const f16* __restrict__ Wpk,
    const float* __restrict__ bo, void* __restrict__ Y)
{
    __shared__ f16 Xl[32 * 512];
    const int wg  = blockIdx.x;
    const int xcd = wg & 7;
    const int i   = wg >> 3;
    const int pg  = xcd * 64 + i;       // 0..511
    const int cb  = pg & 1;
    const int y   = pg >> 1;
    gemm_stream_core<1, 1, 0, 4, 2>(X, Wpk + 786432, bo, Y, y * 32, cb * 256, Xl);
}

// ---------------------------------------------------------------------------
// ZERO-LDS MFMA flash attention, fragment-packed K/V inputs.
// Every K/V fragment load = 64 lanes x 16B = 1KB CONTIGUOUS (16 full lines).
// Structure otherwise identical to the proven R6/R15 kernel.
// ---------------------------------------------------------------------------
__global__ __launch_bounds__(64) void attn_kernel(
    const f16* __restrict__ Q, const f16* __restrict__ Kpk,
    const f16* __restrict__ Vpk, const float* __restrict__ Wg,
    const float* __restrict__ bg, const float* __restrict__ lam1,
    f16* __restrict__ ATT)
{
    const int lane = threadIdx.x;     // 0..63
    const int lq   = lane & 31;
    const int half = lane >> 5;
    const int bh   = blockIdx.x;      // same bh -> same XCD
    const int b    = bh >> 3;
    const int h    = bh & 7;
    const int q0w  = blockIdx.y * 32;
    const int q    = q0w + lq;

    const float sg  = 1.f / (1.f + __expf(-lam1[0]));
    const float osg = 1.f - sg;

    // Q fragments (B-operand)
    f16x8 qh[4];
    {
        const f16* qrow = Q + ((size_t)(b * L_ + q) * DM_ + h * DK_);
        #pragma unroll
        for (int db = 0; db < 4; ++db)
            qh[db] = *(const f16x8*)&qrow[db * 16 + 8 * half];
    }

    // fused gamma: g = q_row . Wg^T + bg ; qp = (|g|+1)^-2
    float A0, A1, qpw;
    {
        float g0 = 0.f, g1 = 0.f;
        #pragma unroll
        for (int db = 0; db < 4; ++db)
            #pragma unroll
            for (int j = 0; j < 8; ++j) {
                const int d = db * 16 + 8 * half + j;
                const float qv = (float)qh[db][j];
                g0 = fmaf(qv, Wg[d], g0);
                g1 = fmaf(qv, Wg[64 + d], g1);
            }
        g0 += __shfl_xor(g0, 32);
        g1 += __shfl_xor(g1, 32);
        g0 += bg[0];
        g1 += bg[1];
        const float t0 = fabsf(g0) + 1.f, t1 = fabsf(g1) + 1.f;
        const float p0 = 1.f / (t0 * t0), p1 = 1.f / (t1 * t1);
        A0 = -NLOG2E_H_ * p0;       // c >= q (triu)
        A1 = -NLOG2E_H_ * p1;       // c <  q (tril)
        float mn = NLOG2E_H_ * fminf(p0, p1);
        #pragma unroll
        for (int off = 1; off < 64; off <<= 1) mn = fminf(mn, __shfl_xor(mn, off));
        qpw = mn;
    }

    f32x16 aS0, aS1, aA0, aA1;
    #pragma unroll
    for (int i = 0; i < 16; ++i) { aS0[i] = 0.f; aS1[i] = 0.f; aA0[i] = 0.f; aA1[i] = 0.f; }
    float m2 = -3.0e38f, sumS = 0.f, sumA = 0.f;

    const f16* Kp = Kpk + (size_t)(b * H_ + h) * 32768;
    const f16* Vp = Vpk + (size_t)(b * H_ + h) * 32768;
    const int  fo = half * 256 + lq * 8;   // in-fragment offset (f16)

    for (int t = 0; t < 8; ++t) {
        const int c0 = t * 64;

        // fully-coalesced packed fragment loads (1KB contiguous per instr)
        f16x8 ka[4], kb2[4], vfa[4], vfb[4];
        #pragma unroll
        for (int db = 0; db < 4; ++db) {
            ka[db]  = *(const f16x8*)&Kp[(t * 2 * 4 + db) * 512 + fo];
            kb2[db] = *(const f16x8*)&Kp[((t * 2 + 1) * 4 + db) * 512 + fo];
        }
        #pragma unroll
        for (int ks = 0; ks < 4; ++ks) {
            vfa[ks] = *(const f16x8*)&Vp[((t * 4 + ks) * 2 + 0) * 512 + fo];
            vfb[ks] = *(const f16x8*)&Vp[((t * 4 + ks) * 2 + 1) * 512 + fo];
        }

        // S^T = K . Q^T
        f32x16 s2a, s2b;
        #pragma unroll
        for (int i = 0; i < 16; ++i) { s2a[i] = 0.f; s2b[i] = 0.f; }
        #pragma unroll
        for (int db = 0; db < 4; ++db) {
            s2a = __builtin_amdgcn_mfma_f32_32x32x16_f16(ka[db],  qh[db], s2a, 0, 0, 0);
            s2b = __builtin_amdgcn_mfma_f32_32x32x16_f16(kb2[db], qh[db], s2b, 0, 0, 0);
        }

        // online max with skip-rescale
        float tm = s2a[0];
        #pragma unroll
        for (int i = 1; i < 16; ++i) tm = fmaxf(tm, s2a[i]);
        #pragma unroll
        for (int i = 0; i < 16; ++i) tm = fmaxf(tm, s2b[i]);
        tm = fmaxf(tm, __shfl_xor(tm, 32));
        if (__any(tm > m2)) {
            const float nm = fmaxf(m2, tm);
            const float sc = exp2f((m2 - nm) * LOG2E_);
            m2 = nm;
            sumS *= sc;
            #pragma unroll
            for (int r = 0; r < 16; ++r) {
                const float s_ = __shfl(sc, (r & 3) + 8 * (r >> 2) + 4 * half);
                aS0[r] *= s_;
                aS1[r] *= s_;
            }
        }

        // P: exp, pack, permlane-swap into A-fragments, PV MFMAs
        const float nmL = m2 * LOG2E_;
        #pragma unroll
        for (int sub = 0; sub < 2; ++sub) {
            const f32x16& s2 = sub ? s2b : s2a;
            #pragma unroll
            for (int ksl = 0; ksl < 2; ++ksl) {
                const int rb = ksl * 8;
                float p[8];
                #pragma unroll
                for (int rr = 0; rr < 8; ++rr) {
                    p[rr] = exp2f(fmaf(s2[rb + rr], LOG2E_, -nmL));
                    sumS += p[rr];
                }
                union { unsigned u[4]; f16x8 v; } f;
                f.u[0] = pkrtz(p[0], p[1]);
                f.u[1] = pkrtz(p[2], p[3]);
                f.u[2] = pkrtz(p[4], p[5]);
                f.u[3] = pkrtz(p[6], p[7]);
                plswap(f.u[0], f.u[2]);
                plswap(f.u[1], f.u[3]);
                const int ks = sub * 2 + ksl;
                aS0 = __builtin_amdgcn_mfma_f32_32x32x16_f16(f.v, vfa[ks], aS0, 0, 0, 0);
                aS1 = __builtin_amdgcn_mfma_f32_32x32x16_f16(f.v, vfb[ks], aS1, 0, 0, 0);
            }
        }

        // adjacency branch (band-skip far tiles; diagonal tile never skipped)
        int gl_ = q0w - (c0 + 63);
        int gh_ = c0 - (q0w + 31);
        int dmin = gl_ > gh_ ? gl_ : gh_;
        if (dmin < 0) dmin = 0;
        if (qpw * (float)(dmin * dmin) < 40.0f) {
            #pragma unroll
            for (int sub = 0; sub < 2; ++sub) {
                #pragma unroll
                for (int ksl = 0; ksl < 2; ++ksl) {
                    float a[8];
                    #pragma unroll
                    for (int rr = 0; rr < 8; ++rr) {
                        const int kk = (rr & 3) + 8 * (rr >> 2) + 16 * ksl + 4 * half;
                        const int diff = q - (c0 + sub * 32 + kk);
                        const float fd = (float)diff;
                        const float coef = diff > 0 ? A1 : A0;
                        a[rr] = exp2f(coef * fd * fd);
                        sumA += a[rr];
                    }
                    union { unsigned u[4]; f16x8 v; } f;
                    f.u[0] = pkrtz(a[0], a[1]);
                    f.u[1] = pkrtz(a[2], a[3]);
                    f.u[2] = pkrtz(a[4], a[5]);
                    f.u[3] = pkrtz(a[6], a[7]);
                    plswap(f.u[0], f.u[2]);
                    plswap(f.u[1], f.u[3]);
                    const int ks = sub * 2 + ksl;
                    aA0 = __builtin_amdgcn_mfma_f32_32x32x16_f16(f.v, vfa[ks], aA0, 0, 0, 0);
                    aA1 = __builtin_amdgcn_mfma_f32_32x32x16_f16(f.v, vfb[ks], aA1, 0, 0, 0);
                }
            }
        }
    }

    // epilogue: mix branches, degree-normalize, store
    const float St = sumS + __shfl_xor(sumS, 32);
    const float At = sumA + __shfl_xor(sumA, 32);
    const float den = sg * St + osg * At + 1e-9f;
    #pragma unroll
    for (int r = 0; r < 16; ++r) {
        const int row = (r & 3) + 8 * (r >> 2) + 4 * half;
        const float dn = __shfl(den, row);
        const float o0 = (sg * aS0[r] + osg * aA0[r]) / dn;
        const float o1 = (sg * aS1[r] + osg * aA1[r]) / dn;
        const size_t base = (size_t)(b * L_ + q0w + row) * DM_ + h * DK_;
        ATT[base + lq]      = (f16)o0;
        ATT[base + 32 + lq] = (f16)o1;
    }
}

// ---------------------------------------------------------------------------
extern "C" void kernel_launch(void* const* d_in, const int* in_sizes, int n_in,
                              void* d_out, int out_size, void* d_ws, size_t ws_size,
                              hipStream_t stream)
{
    (void)in_sizes; (void)n_in; (void)out_size; (void)ws_size;
    const float* query = (const float*)d_in[0];
    const float* key   = (const float*)d_in[1];
    const float* value = (const float*)d_in[2];
    const float* Wq = (const float*)d_in[3];  const float* bq = (const float*)d_in[4];
    const float* Wk = (const float*)d_in[5];  const float* bk = (const float*)d_in[6];
    const float* Wv = (const float*)d_in[7];  const float* bv = (const float*)d_in[8];
    const float* Wg = (const float*)d_in[9];  const float* bg = (const float*)d_in[10];
    const float* lam1 = (const float*)d_in[11];
    const float* Wo = (const float*)d_in[12]; const float* bo = (const float*)d_in[13];

    f16* ws16 = (f16*)d_ws;
    const size_t NR = (size_t)B_ * L_ * DM_;      // 4 Mi elements
    f16* Kpkb = ws16;                             // 128 x 32768 f16 = 8 MB
    f16* Vpkb = ws16 + NR;                        // 8 MB
    f16* Qb   = ws16 + 2 * NR;
    f16* Wpkb = ws16 + 3 * NR;                    // 2 MB
    f16* ATTb = Qb;   // safe alias: each wave reads exactly the Q cells it later writes

    convw_pack<<<512, 256, 0, stream>>>(Wq, Wk, Wv, Wo, Wpkb);

    gemm_qkv<<<768, 512, 0, stream>>>(query, key, value, Wpkb, bq, bk, bv,
                                      Qb, Kpkb, Vpkb);

    dim3 ga(H_ * B_, L_ / 32);    // (128, 16), 64 threads = 1 wave per block
    attn_kernel<<<ga, 64, 0, stream>>>(Qb, Kpkb, Vpkb, Wg, bg, lam1, ATTb);

    gemm_o<<<512, 256, 0, stream>>>(Qb, Wpkb, bo, (float*)d_out);
}

// Round 18
// 75.626 us; speedup vs baseline: 2.5018x; 1.2074x over previous
//
#include <hip/hip_runtime.h>
#include <hip/hip_fp16.h>
#include <math.h>

#define B_  16
#define H_  8
#define L_  512
#define DM_ 512
#define DK_ 64
#define LOG2E_ 1.44269504088896340736f
#define NLOG2E_H_ 0.72134752044f   // 0.5 * log2(e)

typedef _Float16 f16;
typedef __attribute__((ext_vector_type(2)))  __fp16   fp16v2;
typedef __attribute__((ext_vector_type(8)))  _Float16 f16x8;
typedef __attribute__((ext_vector_type(16))) float f32x16;

__device__ __forceinline__ unsigned pkrtz(float a, float b) {
    union { fp16v2 v; unsigned u; } cv;
    cv.v = __builtin_amdgcn_cvt_pkrtz(a, b);
    return cv.u;
}
// v_permlane32_swap_b32: x[lanes 32..63] <-> y[lanes 0..31]
__device__ __forceinline__ void plswap(unsigned &x, unsigned &y) {
    asm("v_permlane32_swap_b32 %0, %1" : "+v"(x), "+v"(y));
}

// ---------------------------------------------------------------------------
// W pre-pack (unchanged): Wpk[nb][ks][hf][lane][8].
// ---------------------------------------------------------------------------
__global__ __launch_bounds__(256) void convw_pack(
    const float* __restrict__ Wq, const float* __restrict__ Wk,
    const float* __restrict__ Wv, const float* __restrict__ Wo,
    f16* __restrict__ Wpk)
{
    const float* src[4] = {Wq, Wk, Wv, Wo};
    const int t = blockIdx.x * 256 + threadIdx.x;
    const int m    = t >> 15;
    const int r    = t & 32767;
    const int lane = r & 31;
    const int hf   = (r >> 5) & 1;
    const int ks   = (r >> 6) & 31;
    const int nb   = r >> 11;
    const float* p = src[m] + (size_t)(nb * 32 + lane) * 512 + ks * 16 + hf * 8;
    float4 x0 = *(const float4*)(p);
    float4 x1 = *(const float4*)(p + 4);
    uint4 v;
    v.x = pkrtz(x0.x, x0.y); v.y = pkrtz(x0.z, x0.w);
    v.z = pkrtz(x1.x, x1.y); v.w = pkrtz(x1.z, x1.w);
    *(uint4*)&Wpk[(size_t)m * 262144 + (size_t)r * 8] = v;
}

// ---------------------------------------------------------------------------
// Stream GEMM core (unchanged from R16).  OUTMODE: 0 row-major, 1 Vpk, 2 Kpk.
// ---------------------------------------------------------------------------
template<int XF16, int OUTF32, int OUTMODE, int NWAVES, int NT>
__device__ __forceinline__ void gemm_stream_core(
    const void* __restrict__ Xv, const f16* __restrict__ Wpk_m,
    const float* __restrict__ bias, void* __restrict__ Yv,
    int row0, int col0, f16* Xl)
{
    const int tid   = threadIdx.x;
    const int w     = tid >> 6;
    const int lane  = tid & 63;
    const int lq    = lane & 31;
    const int half_ = lane >> 5;
    const int colw  = col0 + w * (NT * 32);

    {
        constexpr int TPR = NWAVES * 64 / 32;
        constexpr int FPT = 512 / TPR;
        const int r = tid / TPR, s = tid % TPR;
        const unsigned swz = (r & 7) << 4;
        if (XF16) {
            const f16* X = (const f16*)Xv + (size_t)(row0 + r) * 512 + s * FPT;
            #pragma unroll
            for (int j = 0; j < FPT / 8; ++j) {
                uint4 v = *(const uint4*)(X + j * 8);
                *(uint4*)((char*)Xl + ((r * 1024 + s * FPT * 2 + j * 16) ^ swz)) = v;
            }
        } else {
            const float* X = (const float*)Xv + (size_t)(row0 + r) * 512 + s * FPT;
            #pragma unroll
            for (int j = 0; j < FPT / 8; ++j) {
                float4 x0 = *(const float4*)(X + j * 8);
                float4 x1 = *(const float4*)(X + j * 8 + 4);
                uint4 v;
                v.x = pkrtz(x0.x, x0.y); v.y = pkrtz(x0.z, x0.w);
                v.z = pkrtz(x1.x, x1.y); v.w = pkrtz(x1.z, x1.w);
                *(uint4*)((char*)Xl + ((r * 1024 + s * FPT * 2 + j * 16) ^ swz)) = v;
            }
        }
    }
    __syncthreads();

    f32x16 acc[NT];
    #pragma unroll
    for (int nt = 0; nt < NT; ++nt)
        #pragma unroll
        for (int i = 0; i < 16; ++i) acc[nt][i] = 0.f;

    const f16* wp[NT];
    #pragma unroll
    for (int nt = 0; nt < NT; ++nt)
        wp[nt] = Wpk_m + ((size_t)((colw / 32 + nt) * 64 + half_)) * 256 + lq * 8;

    const unsigned aswz = (lq & 7) << 4;

    #pragma unroll 4
    for (int ks = 0; ks < 32; ++ks) {
        f16x8 a = *(const f16x8*)((char*)Xl + ((lq * 1024 + ks * 32 + half_ * 16) ^ aswz));
        f16x8 bfr[NT];
        #pragma unroll
        for (int nt = 0; nt < NT; ++nt)
            bfr[nt] = *(const f16x8*)(wp[nt] + (size_t)ks * 512);
        #pragma unroll
        for (int nt = 0; nt < NT; ++nt) {
            if (OUTMODE == 2)
                acc[nt] = __builtin_amdgcn_mfma_f32_32x32x16_f16(bfr[nt], a, acc[nt], 0, 0, 0);
            else
                acc[nt] = __builtin_amdgcn_mfma_f32_32x32x16_f16(a, bfr[nt], acc[nt], 0, 0, 0);
        }
    }

    if (OUTMODE == 2) {
        const int b  = row0 >> 9;
        const int cb = (row0 >> 5) & 15;
        f16* Kp = (f16*)Yv + (size_t)(b * H_ + w) * 32768;
        #pragma unroll
        for (int nt = 0; nt < NT; ++nt)
            #pragma unroll
            for (int g = 0; g < 4; ++g) {
                const int n0 = w * 64 + nt * 32 + 8 * g + 4 * half_;
                const float4 b4 = *(const float4*)&bias[n0];
                const int ks2 = nt * 2 + (g >> 1);
                uint2 v;
                v.x = pkrtz(acc[nt][4 * g + 0] + b4.x, acc[nt][4 * g + 1] + b4.y);
                v.y = pkrtz(acc[nt][4 * g + 2] + b4.z, acc[nt][4 * g + 3] + b4.w);
                *(uint2*)&Kp[(cb * 4 + ks2) * 512 + (g & 1) * 256 + lq * 8 + half_ * 4] = v;
            }
    } else if (OUTMODE == 1) {
        const int b  = row0 >> 9;
        const int cB = row0 & 511;
        const int tt = cB >> 6;
        const int kbase = (cB >> 4) & 3;
        f16* Vp = (f16*)Yv + (size_t)(b * H_ + w) * 32768;
        #pragma unroll
        for (int nt = 0; nt < NT; ++nt) {
            const float bv = bias[w * 64 + nt * 32 + lq];
            #pragma unroll
            for (int g = 0; g < 4; ++g) {
                const int ks2 = kbase + (g >> 1);
                uint2 v;
                v.x = pkrtz(acc[nt][4 * g + 0] + bv, acc[nt][4 * g + 1] + bv);
                v.y = pkrtz(acc[nt][4 * g + 2] + bv, acc[nt][4 * g + 3] + bv);
                *(uint2*)&Vp[((tt * 4 + ks2) * 2 + nt) * 512 + (g & 1) * 256 + lq * 8 + half_ * 4] = v;
            }
        }
    } else {
        #pragma unroll
        for (int nt = 0; nt < NT; ++nt) {
            const float bv = bias[colw + nt * 32 + lq];
            #pragma unroll
            for (int r = 0; r < 16; ++r) {
                const int row = row0 + (r & 3) + 8 * (r >> 2) + 4 * half_;
                const float v = acc[nt][r] + bv;
                const size_t off = (size_t)row * 512 + colw + nt * 32 + lq;
                if (OUTF32) ((float*)Yv)[off] = v;
                else        ((f16*)Yv)[off]   = (f16)v;
            }
        }
    }
}

__global__ __launch_bounds__(512) void gemm_qkv(
    const float* __restrict__ query, const float* __restrict__ key,
    const float* __restrict__ value, const f16* __restrict__ Wpk,
    const float* __restrict__ bq, const float* __restrict__ bk,
    const float* __restrict__ bv,
    void* __restrict__ Qb, void* __restrict__ Kpk, void* __restrict__ Vpk)
{
    __shared__ f16 Xl[32 * 512];
    const int wg  = blockIdx.x;
    const int xcd = wg & 7;
    const int i   = wg >> 3;
    const int pg  = xcd * 96 + i;
    const int z   = pg >> 8;
    const int y   = pg & 255;
    const int row0 = y * 32;

    if (z == 0)
        gemm_stream_core<0, 0, 0, 8, 2>(query, Wpk,          bq, Qb,  row0, 0, Xl);
    else if (z == 1)
        gemm_stream_core<0, 0, 2, 8, 2>(key,   Wpk + 262144, bk, Kpk, row0, 0, Xl);
    else
        gemm_stream_core<0, 0, 1, 8, 2>(value, Wpk + 524288, bv, Vpk, row0, 0, Xl);
}

__global__ __launch_bounds__(256) void gemm_o(
    const void* __restrict__ X, const f16* __restrict__ Wpk,
    const float* __restrict__ bo, void* __restrict__ Y)
{
    __shared__ f16 Xl[32 * 512];
    const int wg  = blockIdx.x;
    const int xcd = wg & 7;
    const int i   = wg >> 3;
    const int pg  = xcd * 64 + i;
    const int cb  = pg & 1;
    const int y   = pg >> 1;
    gemm_stream_core<1, 1, 0, 4, 2>(X, Wpk + 786432, bo, Y, y * 32, cb * 256, Xl);
}

// ---------------------------------------------------------------------------
// Flash attention: 4 INDEPENDENT waves per 256-thread block (no LDS, no
// barriers).  Exact-skip rescale (defer-max REMOVED: the sigmoid-gated mix
// with the adjacency branch is NOT scale-invariant, so P must be relative to
// the true running max).  s_setprio around MFMA clusters (T5).
// ---------------------------------------------------------------------------
__global__ __launch_bounds__(256) void attn_kernel(
    const f16* __restrict__ Q, const f16* __restrict__ Kpk,
    const f16* __restrict__ Vpk, const float* __restrict__ Wg,
    const float* __restrict__ bg, const float* __restrict__ lam1,
    f16* __restrict__ ATT)
{
    const int tid  = threadIdx.x;
    const int w    = tid >> 6;        // independent wave id
    const int lane = tid & 63;
    const int lq   = lane & 31;
    const int half = lane >> 5;
    const int bh   = blockIdx.x;      // same bh -> same XCD
    const int b    = bh >> 3;
    const int h    = bh & 7;
    const int q0w  = blockIdx.y * 128 + w * 32;
    const int q    = q0w + lq;

    const float sg  = 1.f / (1.f + __expf(-lam1[0]));
    const float osg = 1.f - sg;

    // Q fragments (B-operand)
    f16x8 qh[4];
    {
        const f16* qrow = Q + ((size_t)(b * L_ + q) * DM_ + h * DK_);
        #pragma unroll
        for (int db = 0; db < 4; ++db)
            qh[db] = *(const f16x8*)&qrow[db * 16 + 8 * half];
    }

    // fused gamma: g = q_row . Wg^T + bg ; qp = (|g|+1)^-2
    float A0, A1, qpw;
    {
        float g0 = 0.f, g1 = 0.f;
        #pragma unroll
        for (int db = 0; db < 4; ++db)
            #pragma unroll
            for (int j = 0; j < 8; ++j) {
                const int d = db * 16 + 8 * half + j;
                const float qv = (float)qh[db][j];
                g0 = fmaf(qv, Wg[d], g0);
                g1 = fmaf(qv, Wg[64 + d], g1);
            }
        g0 += __shfl_xor(g0, 32);
        g1 += __shfl_xor(g1, 32);
        g0 += bg[0];
        g1 += bg[1];
        const float t0 = fabsf(g0) + 1.f, t1 = fabsf(g1) + 1.f;
        const float p0 = 1.f / (t0 * t0), p1 = 1.f / (t1 * t1);
        A0 = -NLOG2E_H_ * p0;       // c >= q (triu)
        A1 = -NLOG2E_H_ * p1;       // c <  q (tril)
        float mn = NLOG2E_H_ * fminf(p0, p1);
        #pragma unroll
        for (int off = 1; off < 64; off <<= 1) mn = fminf(mn, __shfl_xor(mn, off));
        qpw = mn;
    }

    f32x16 aS0, aS1, aA0, aA1;
    #pragma unroll
    for (int i = 0; i < 16; ++i) { aS0[i] = 0.f; aS1[i] = 0.f; aA0[i] = 0.f; aA1[i] = 0.f; }
    float m2 = -3.0e38f, sumS = 0.f, sumA = 0.f;

    const f16* Kp = Kpk + (size_t)(b * H_ + h) * 32768;
    const f16* Vp = Vpk + (size_t)(b * H_ + h) * 32768;
    const int  fo = half * 256 + lq * 8;

    for (int t = 0; t < 8; ++t) {
        const int c0 = t * 64;

        // fully-coalesced packed fragment loads (1KB contiguous per instr)
        f16x8 ka[4], kb2[4], vfa[4], vfb[4];
        #pragma unroll
        for (int db = 0; db < 4; ++db) {
            ka[db]  = *(const f16x8*)&Kp[(t * 2 * 4 + db) * 512 + fo];
            kb2[db] = *(const f16x8*)&Kp[((t * 2 + 1) * 4 + db) * 512 + fo];
        }
        #pragma unroll
        for (int ks = 0; ks < 4; ++ks) {
            vfa[ks] = *(const f16x8*)&Vp[((t * 4 + ks) * 2 + 0) * 512 + fo];
            vfb[ks] = *(const f16x8*)&Vp[((t * 4 + ks) * 2 + 1) * 512 + fo];
        }

        // S^T = K . Q^T
        f32x16 s2a, s2b;
        #pragma unroll
        for (int i = 0; i < 16; ++i) { s2a[i] = 0.f; s2b[i] = 0.f; }
        __builtin_amdgcn_s_setprio(1);
        #pragma unroll
        for (int db = 0; db < 4; ++db) {
            s2a = __builtin_amdgcn_mfma_f32_32x32x16_f16(ka[db],  qh[db], s2a, 0, 0, 0);
            s2b = __builtin_amdgcn_mfma_f32_32x32x16_f16(kb2[db], qh[db], s2b, 0, 0, 0);
        }
        __builtin_amdgcn_s_setprio(0);

        // online max, exact skip (rescale only when the max actually moves)
        float tm = s2a[0];
        #pragma unroll
        for (int i = 1; i < 16; ++i) tm = fmaxf(tm, s2a[i]);
        #pragma unroll
        for (int i = 0; i < 16; ++i) tm = fmaxf(tm, s2b[i]);
        tm = fmaxf(tm, __shfl_xor(tm, 32));
        if (__any(tm > m2)) {
            const float nm = fmaxf(m2, tm);
            const float sc = exp2f((m2 - nm) * LOG2E_);
            m2 = nm;
            sumS *= sc;
            #pragma unroll
            for (int r = 0; r < 16; ++r) {
                const float s_ = __shfl(sc, (r & 3) + 8 * (r >> 2) + 4 * half);
                aS0[r] *= s_;
                aS1[r] *= s_;
            }
        }

        // P: exp, pack, permlane-swap into A-fragments, PV MFMAs
        const float nmL = m2 * LOG2E_;
        #pragma unroll
        for (int sub = 0; sub < 2; ++sub) {
            const f32x16& s2 = sub ? s2b : s2a;
            #pragma unroll
            for (int ksl = 0; ksl < 2; ++ksl) {
                const int rb = ksl * 8;
                float p[8];
                #pragma unroll
                for (int rr = 0; rr < 8; ++rr) {
                    p[rr] = exp2f(fmaf(s2[rb + rr], LOG2E_, -nmL));
                    sumS += p[rr];
                }
                union { unsigned u[4]; f16x8 v; } f;
                f.u[0] = pkrtz(p[0], p[1]);
                f.u[1] = pkrtz(p[2], p[3]);
                f.u[2] = pkrtz(p[4], p[5]);
                f.u[3] = pkrtz(p[6], p[7]);
                plswap(f.u[0], f.u[2]);
                plswap(f.u[1], f.u[3]);
                const int ks = sub * 2 + ksl;
                __builtin_amdgcn_s_setprio(1);
                aS0 = __builtin_amdgcn_mfma_f32_32x32x16_f16(f.v, vfa[ks], aS0, 0, 0, 0);
                aS1 = __builtin_amdgcn_mfma_f32_32x32x16_f16(f.v, vfb[ks], aS1, 0, 0, 0);
                __builtin_amdgcn_s_setprio(0);
            }
        }

        // adjacency branch (band-skip far tiles; diagonal tile never skipped)
        int gl_ = q0w - (c0 + 63);
        int gh_ = c0 - (q0w + 31);
        int dmin = gl_ > gh_ ? gl_ : gh_;
        if (dmin < 0) dmin = 0;
        if (qpw * (float)(dmin * dmin) < 40.0f) {
            #pragma unroll
            for (int sub = 0; sub < 2; ++sub) {
                #pragma unroll
                for (int ksl = 0; ksl < 2; ++ksl) {
                    float a[8];
                    #pragma unroll
                    for (int rr = 0; rr < 8; ++rr) {
                        const int kk = (rr & 3) + 8 * (rr >> 2) + 16 * ksl + 4 * half;
                        const int diff = q - (c0 + sub * 32 + kk);
                        const float fd = (float)diff;
                        const float coef = diff > 0 ? A1 : A0;
                        a[rr] = exp2f(coef * fd * fd);
                        sumA += a[rr];
                    }
                    union { unsigned u[4]; f16x8 v; } f;
                    f.u[0] = pkrtz(a[0], a[1]);
                    f.u[1] = pkrtz(a[2], a[3]);
                    f.u[2] = pkrtz(a[4], a[5]);
                    f.u[3] = pkrtz(a[6], a[7]);
                    plswap(f.u[0], f.u[2]);
                    plswap(f.u[1], f.u[3]);
                    const int ks = sub * 2 + ksl;
                    __builtin_amdgcn_s_setprio(1);
                    aA0 = __builtin_amdgcn_mfma_f32_32x32x16_f16(f.v, vfa[ks], aA0, 0, 0, 0);
                    aA1 = __builtin_amdgcn_mfma_f32_32x32x16_f16(f.v, vfb[ks], aA1, 0, 0, 0);
                    __builtin_amdgcn_s_setprio(0);
                }
            }
        }
    }

    // epilogue: mix branches, degree-normalize, store
    const float St = sumS + __shfl_xor(sumS, 32);
    const float At = sumA + __shfl_xor(sumA, 32);
    const float den = sg * St + osg * At + 1e-9f;
    #pragma unroll
    for (int r = 0; r < 16; ++r) {
        const int row = (r & 3) + 8 * (r >> 2) + 4 * half;
        const float dn = __shfl(den, row);
        const float o0 = (sg * aS0[r] + osg * aA0[r]) / dn;
        const float o1 = (sg * aS1[r] + osg * aA1[r]) / dn;
        const size_t base = (size_t)(b * L_ + q0w + row) * DM_ + h * DK_;
        ATT[base + lq]      = (f16)o0;
        ATT[base + 32 + lq] = (f16)o1;
    }
}

// ---------------------------------------------------------------------------
extern "C" void kernel_launch(void* const* d_in, const int* in_sizes, int n_in,
                              void* d_out, int out_size, void* d_ws, size_t ws_size,
                              hipStream_t stream)
{
    (void)in_sizes; (void)n_in; (void)out_size; (void)ws_size;
    const float* query = (const float*)d_in[0];
    const float* key   = (const float*)d_in[1];
    const float* value = (const float*)d_in[2];
    const float* Wq = (const float*)d_in[3];  const float* bq = (const float*)d_in[4];
    const float* Wk = (const float*)d_in[5];  const float* bk = (const float*)d_in[6];
    const float* Wv = (const float*)d_in[7];  const float* bv = (const float*)d_in[8];
    const float* Wg = (const float*)d_in[9];  const float* bg = (const float*)d_in[10];
    const float* lam1 = (const float*)d_in[11];
    const float* Wo = (const float*)d_in[12]; const float* bo = (const float*)d_in[13];

    f16* ws16 = (f16*)d_ws;
    const size_t NR = (size_t)B_ * L_ * DM_;
    f16* Kpkb = ws16;
    f16* Vpkb = ws16 + NR;
    f16* Qb   = ws16 + 2 * NR;
    f16* Wpkb = ws16 + 3 * NR;
    f16* ATTb = Qb;   // safe alias: each wave reads exactly the Q cells it later writes

    convw_pack<<<512, 256, 0, stream>>>(Wq, Wk, Wv, Wo, Wpkb);

    gemm_qkv<<<768, 512, 0, stream>>>(query, key, value, Wpkb, bq, bk, bv,
                                      Qb, Kpkb, Vpkb);

    dim3 ga(H_ * B_, L_ / 128);   // (128, 4) x 256 thr = 4 independent waves/block
    attn_kernel<<<ga, 256, 0, stream>>>(Qb, Kpkb, Vpkb, Wg, bg, lam1, ATTb);

    gemm_o<<<512, 256, 0, stream>>>(Qb, Wpkb, bo, (float*)d_out);
}